// Round 1
// 1403.711 us; speedup vs baseline: 1.0118x; 1.0118x over previous
//
#include <hip/hip_runtime.h>
#include <hip/hip_fp16.h>

#define DD 32
#define NLAYERS 8
#define TOPK 8
#define NXCD 8
#define SCHUNK 4096

typedef _Float16 half8 __attribute__((ext_vector_type(8)));
typedef float f32x4 __attribute__((ext_vector_type(4)));

__device__ __forceinline__ unsigned encf(float x){ unsigned u=__float_as_uint(x); return (u&0x80000000u)? ~u : (u|0x80000000u); }
__device__ __forceinline__ unsigned short f2h(float f){ return __half_as_ushort(__float2half(f)); }
__device__ __forceinline__ float h2f(unsigned short u){ return __half2float(__ushort_as_half(u)); }
__device__ __forceinline__ float4 up4(uint2 u){
  float4 r;
  r.x=h2f((unsigned short)(u.x&0xFFFFu)); r.y=h2f((unsigned short)(u.x>>16));
  r.z=h2f((unsigned short)(u.y&0xFFFFu)); r.w=h2f((unsigned short)(u.y>>16));
  return r;
}
union HU { uint2 u; half8 h; };   // b-fragment reinterpret (8 fp16 = 4 VGPRs... 2x uint2)
union HU4 { uint4 u; half8 h; };
__device__ __forceinline__ int gidx(const void* p, long i, int i64){
  return i64 ? (int)((const long long*)p)[i] : ((const int*)p)[i];
}

__global__ void k_detect(const int* __restrict__ srcw, int* __restrict__ iflag){
  if (threadIdx.x==0 && blockIdx.x==0){
    int allz = 1;
    for (int k=1;k<32;k+=2) if (srcw[k]!=0) allz = 0;
    *iflag = allz;
  }
}

__global__ void k_zero(int* cnt, int* cursor, int N){
  int n = blockIdx.x*blockDim.x + threadIdx.x;
  if (n<N){ cnt[n]=0; cursor[n]=0; }
}

// h16 = fp16(relu(tok_emb[h_tok])) ; in-degree histogram
__global__ void k_init(const void* __restrict__ h_tok, const void* __restrict__ dstv,
                       const float* __restrict__ tok_emb,
                       unsigned short* __restrict__ h16, int* __restrict__ cnt,
                       const int* __restrict__ iflag, int N, int E)
{
  int i64 = *iflag;
  long idx = (long)blockIdx.x*blockDim.x + threadIdx.x;
  if (idx < (long)N*8){
    int n=(int)(idx>>3), q=(int)(idx&7);
    int t = gidx(h_tok, n, i64);
    float4 v = reinterpret_cast<const float4*>(tok_emb)[t*8+q];
    uint2 o;
    o.x = (unsigned)f2h(fmaxf(v.x,0.f)) | ((unsigned)f2h(fmaxf(v.y,0.f))<<16);
    o.y = (unsigned)f2h(fmaxf(v.z,0.f)) | ((unsigned)f2h(fmaxf(v.w,0.f))<<16);
    reinterpret_cast<uint2*>(h16)[(long)n*8+q] = o;
    return;
  }
  idx -= (long)N*8;
  if (idx < E){
    atomicAdd(&cnt[gidx(dstv, idx, i64)], 1);
  }
}

// single-block exclusive scan of in-degrees -> csr_off (wave shuffle-scan)
__global__ __launch_bounds__(1024) void k_scan(const int* __restrict__ cnt, int* __restrict__ off,
                                               int N, int E){
  __shared__ int wsum[16];
  __shared__ int carry_s;
  int tid = threadIdx.x;
  int lane = tid & 63, w = tid >> 6;
  if (tid==0) carry_s = 0;
  __syncthreads();
  for (int base=0; base<N; base+=1024){
    int v = (base+tid<N)? cnt[base+tid] : 0;
    int x = v;
    #pragma unroll
    for (int d=1; d<64; d<<=1){
      int t = __shfl_up(x, d, 64);
      if (lane>=d) x += t;
    }
    if (lane==63) wsum[w] = x;
    __syncthreads();
    if (w==0 && lane<16){
      int y = wsum[lane];
      #pragma unroll
      for (int d=1; d<16; d<<=1){
        int t = __shfl_up(y, d, 64);
        if (lane>=d) y += t;
      }
      wsum[lane] = y;
    }
    __syncthreads();
    int cl = carry_s;
    int wb = (w>0)? wsum[w-1] : 0;
    int tot = wsum[15];
    if (base+tid<N) off[base+tid] = cl + x + wb - v;
    __syncthreads();
    if (tid==0) carry_s = cl + tot;
    __syncthreads();
  }
  if (tid==0) off[N] = E;
}

// CSR positions, dst-region partitioned to defeat write amplification.
// Region r = blockIdx&7 handles dst in [r*npr,(r+1)*npr): its 1.6 MB slice of
// sde8 stays resident in ONE XCD's L2 (blockIdx&7 round-robins onto XCDs), so
// the 8 B scattered records merge in L2 and write back ~once per line instead
// of once per record. Every (region, chunk) pair runs exactly once -> each
// edge is emitted exactly once regardless of actual block->XCD placement.
__global__ __launch_bounds__(256) void k_scatter(
                          const void* __restrict__ srcv, const void* __restrict__ dstv,
                          const int* __restrict__ off, int* __restrict__ cursor,
                          uint2* __restrict__ sde8,
                          const int* __restrict__ iflag, int E, int npr){
  int i64 = *iflag;
  int reg = blockIdx.x & (NXCD-1);
  int chunk = blockIdx.x >> 3;
  int lo = reg * npr;
  int hi = lo + npr;
  long base = (long)chunk * SCHUNK;
  for (int t = threadIdx.x; t < SCHUNK; t += 256){
    long e = base + t;
    if (e >= E) break;                 // e monotonically increases with t
    int d = gidx(dstv, e, i64);
    if (d < lo || d >= hi) continue;
    int s = gidx(srcv, e, i64);
    int pos = off[d] + atomicAdd(&cursor[d], 1);
    uint2 r; r.x = ((unsigned)d<<16) | (unsigned)s; r.y = (unsigned)e;
    sde8[pos] = r;
  }
}

// stream sde8: emit csr_sd sequentially + fill ebuf (fp16) from L1-resident e_emb table
__global__ void k_fill(const uint2* __restrict__ sde8, const void* __restrict__ e_tok,
                       const float* __restrict__ e_emb,
                       unsigned* __restrict__ csr_sd, unsigned short* __restrict__ ebuf,
                       const int* __restrict__ iflag, int E){
  int i64 = *iflag;
  long idx = (long)blockIdx.x*blockDim.x + threadIdx.x;
  if (idx >= (long)E*4) return;
  int pos = (int)(idx>>2), j = (int)(idx&3);
  uint2 r = sde8[pos];
  if (j==0) csr_sd[pos] = r.x;
  int t = gidx(e_tok, (int)r.y, i64);
  const float4* sp = reinterpret_cast<const float4*>(e_emb + t*DD) + j*2;
  float4 x = sp[0], y = sp[1];
  uint4 ov;
  ov.x = (unsigned)f2h(x.x) | ((unsigned)f2h(x.y)<<16);
  ov.y = (unsigned)f2h(x.z) | ((unsigned)f2h(x.w)<<16);
  ov.z = (unsigned)f2h(y.x) | ((unsigned)f2h(y.y)<<16);
  ov.w = (unsigned)f2h(y.z) | ((unsigned)f2h(y.w)<<16);
  reinterpret_cast<uint4*>(ebuf)[(long)pos*4+j] = ov;
}

// hA16=h16@Wni, hB16=h16@Wnj   (first layer only)
__global__ __launch_bounds__(256) void k_nodeAB(
    const unsigned short* __restrict__ h16,
    const float* __restrict__ WA, const float* __restrict__ WB,
    unsigned short* __restrict__ hA16, unsigned short* __restrict__ hB16, int N)
{
  __shared__ float hl[8][DD];
  int tid = threadIdx.x;
  int ln = tid>>5, c = tid&31;
  int n = blockIdx.x*8 + ln;
  hl[ln][c] = (n<N)? h2f(h16[(long)n*DD+c]) : 0.f;
  __syncthreads();
  float a=0.f,b=0.f;
  #pragma unroll
  for (int k=0;k<DD;k++){
    float v = hl[ln][k];
    a = fmaf(v, WA[k*DD+c], a);
    b = fmaf(v, WB[k*DD+c], b);
  }
  if (n<N){ hA16[(long)n*DD+c]=f2h(a); hB16[(long)n*DD+c]=f2h(b); }
}

// MFMA fp16 edge kernel, SOFTWARE-PIPELINED depth 2: one wave = 16 edges.
// D[m][n=edge]=Wf^T·e^T; f=leaky(D+hA[src]+hB[dst]+b); ebuf<-f; lbuf=exp(f·attn)
__global__ __launch_bounds__(256) void k_edge(
    unsigned short* __restrict__ ebuf,
    const unsigned short* __restrict__ hA16, const unsigned short* __restrict__ hB16,
    const unsigned* __restrict__ csr_sd,
    const float* __restrict__ Wf, const float* __restrict__ bvec,
    const float* __restrict__ attn,
    unsigned short* __restrict__ lbuf, int ntiles, int writef)
{
  int lane = threadIdx.x & 63;
  int wid = (blockIdx.x*256 + threadIdx.x) >> 6;
  int nw  = (gridDim.x*256) >> 6;
  int m = lane & 15, q = lane >> 4;
  half8 a0, a1;
  #pragma unroll
  for (int j=0;j<8;j++){
    a0[j] = (_Float16)Wf[(q*8+j)*DD + m];
    a1[j] = (_Float16)Wf[(q*8+j)*DD + 16 + m];
  }
  float4 blo = *reinterpret_cast<const float4*>(bvec + q*4);
  float4 bhi = *reinterpret_cast<const float4*>(bvec + 16 + q*4);
  float4 alo = *reinterpret_cast<const float4*>(attn + q*4);
  float4 ahi = *reinterpret_cast<const float4*>(attn + 16 + q*4);
  f32x4 zero = {0.f,0.f,0.f,0.f};
  // depth-2 preamble: tile0 = fully loaded; tile1 = sd+b loaded
  HU4 b0; b0.u = make_uint4(0,0,0,0);
  HU4 b1; b1.u = make_uint4(0,0,0,0);
  unsigned sd0 = 0, sd1 = 0;
  uint2 gA0_0={0,0}, gA1_0={0,0}, gB0_0={0,0}, gB1_0={0,0};
  if (wid < ntiles){
    long e0 = (long)wid*16 + m;
    sd0 = csr_sd[e0];
    b0.u = *reinterpret_cast<const uint4*>(ebuf + e0*DD + q*8);
    unsigned s = sd0 & 0xFFFFu, d = sd0 >> 16;
    const uint2* pA = reinterpret_cast<const uint2*>(hA16 + (long)s*DD);
    const uint2* pB = reinterpret_cast<const uint2*>(hB16 + (long)d*DD);
    gA0_0=pA[q]; gA1_0=pA[4+q]; gB0_0=pB[q]; gB1_0=pB[4+q];
  }
  if (wid + nw < ntiles){
    long e1 = (long)(wid+nw)*16 + m;
    sd1 = csr_sd[e1];
    b1.u = *reinterpret_cast<const uint4*>(ebuf + e1*DD + q*8);
  }
  for (int t = wid; t < ntiles; t += nw){
    int t1 = t + nw, t2 = t + 2*nw;
    // 1) issue sd/b for tile t+2nw (fully independent)
    unsigned sd2 = 0; HU4 b2; b2.u = make_uint4(0,0,0,0);
    if (t2 < ntiles){
      long e2 = (long)t2*16 + m;
      sd2 = csr_sd[e2];
      b2.u = *reinterpret_cast<const uint4*>(ebuf + e2*DD + q*8);
    }
    // 2) issue gathers for tile t+nw (dep: sd1, resident since last iteration)
    uint2 gA0_1={0,0}, gA1_1={0,0}, gB0_1={0,0}, gB1_1={0,0};
    if (t1 < ntiles){
      unsigned s = sd1 & 0xFFFFu, d = sd1 >> 16;
      const uint2* pA = reinterpret_cast<const uint2*>(hA16 + (long)s*DD);
      const uint2* pB = reinterpret_cast<const uint2*>(hB16 + (long)d*DD);
      gA0_1=pA[q]; gA1_1=pA[4+q]; gB0_1=pB[q]; gB1_1=pB[4+q];
    }
    // 3) MFMA on current tile (b0 resident)
    f32x4 d0 = __builtin_amdgcn_mfma_f32_16x16x32_f16(a0, b0.h, zero, 0,0,0);
    f32x4 d1 = __builtin_amdgcn_mfma_f32_16x16x32_f16(a1, b0.h, zero, 0,0,0);
    // 4) epilogue with current gathers (issued a full iteration ago)
    long tbase = (long)t*16;
    long edge = tbase + m;
    float4 A0 = up4(gA0_0), A1 = up4(gA1_0);
    float4 B0 = up4(gB0_0), B1 = up4(gB1_0);
    float f00 = d0[0]+A0.x+B0.x+blo.x, f01 = d0[1]+A0.y+B0.y+blo.y;
    float f02 = d0[2]+A0.z+B0.z+blo.z, f03 = d0[3]+A0.w+B0.w+blo.w;
    float f10 = d1[0]+A1.x+B1.x+bhi.x, f11 = d1[1]+A1.y+B1.y+bhi.y;
    float f12 = d1[2]+A1.z+B1.z+bhi.z, f13 = d1[3]+A1.w+B1.w+bhi.w;
    f00 = (f00>0.f)?f00:0.01f*f00; f01 = (f01>0.f)?f01:0.01f*f01;
    f02 = (f02>0.f)?f02:0.01f*f02; f03 = (f03>0.f)?f03:0.01f*f03;
    f10 = (f10>0.f)?f10:0.01f*f10; f11 = (f11>0.f)?f11:0.01f*f11;
    f12 = (f12>0.f)?f12:0.01f*f12; f13 = (f13>0.f)?f13:0.01f*f13;
    if (writef){
      uint2 w0, w1;
      w0.x = (unsigned)f2h(f00) | ((unsigned)f2h(f01)<<16);
      w0.y = (unsigned)f2h(f02) | ((unsigned)f2h(f03)<<16);
      w1.x = (unsigned)f2h(f10) | ((unsigned)f2h(f11)<<16);
      w1.y = (unsigned)f2h(f12) | ((unsigned)f2h(f13)<<16);
      *reinterpret_cast<uint2*>(ebuf + edge*DD + q*4) = w0;
      *reinterpret_cast<uint2*>(ebuf + edge*DD + 16 + q*4) = w1;
    }
    float l = f00*alo.x + f01*alo.y + f02*alo.z + f03*alo.w
            + f10*ahi.x + f11*ahi.y + f12*ahi.z + f13*ahi.w;
    l += __shfl_xor(l, 16, 64);
    l += __shfl_xor(l, 32, 64);
    if (lane < 16){
      float lc = fminf(fmaxf(l, -15.f), 10.5f);
      lbuf[tbase + lane] = f2h(__expf(lc));   // max-free softmax weight
    }
    // rotate pipeline
    sd0 = sd1; b0 = b1;
    gA0_0=gA0_1; gA1_0=gA1_1; gB0_0=gB0_1; gB1_0=gB1_1;
    sd1 = sd2; b1 = b2;
  }
}

// per dst node (32 lanes, CSR): g16 = fp16( (sum ex*h16[src]) / (sum ex) )
__global__ __launch_bounds__(256) void k_aggr(
    const unsigned short* __restrict__ h16, const unsigned short* __restrict__ lbuf,
    const int* __restrict__ off, const unsigned* __restrict__ csr_sd,
    unsigned short* __restrict__ g16, int N)
{
  int tid=threadIdx.x;
  int n = blockIdx.x*8 + (tid>>5);
  int c = tid&31;
  if (n>=N) return;
  int o0 = off[n], o1 = off[n+1];
  float num=0.f, den=0.f;
  for (int i=o0;i<o1;i++){
    float ex = h2f(lbuf[i]);
    unsigned s = csr_sd[i] & 0xFFFFu;
    num = fmaf(ex, h2f(h16[(long)s*DD+c]), num);
    den += ex;
  }
  g16[(long)n*DD+c] = f2h((den>0.f) ? num/den : 0.f);
}

// fused proj + next-layer nodeAB: h16 = relu(g@Wnd); hA16 = h@WA; hB16 = h@WB
__global__ __launch_bounds__(256) void k_pnAB(
    const unsigned short* __restrict__ g16, const float* __restrict__ Wnd,
    const float* __restrict__ WA, const float* __restrict__ WB,
    unsigned short* __restrict__ h16,
    unsigned short* __restrict__ hA16, unsigned short* __restrict__ hB16, int N)
{
  __shared__ float gl[8][DD];
  __shared__ float tl[8][DD];
  int tid = threadIdx.x;
  int ln = tid>>5, c = tid&31;
  int n = blockIdx.x*8 + ln;
  gl[ln][c] = (n<N)? h2f(g16[(long)n*DD+c]) : 0.f;
  __syncthreads();
  float t=0.f;
  #pragma unroll
  for (int k=0;k<DD;k++) t = fmaf(gl[ln][k], Wnd[k*DD+c], t);
  t = fmaxf(t, 0.f);
  tl[ln][c] = t;
  __syncthreads();
  float a=0.f,b=0.f;
  #pragma unroll
  for (int k=0;k<DD;k++){
    float v = tl[ln][k];
    a = fmaf(v, WA[k*DD+c], a);
    b = fmaf(v, WB[k*DD+c], b);
  }
  if (n<N){
    h16[(long)n*DD+c]=f2h(t);
    hA16[(long)n*DD+c]=f2h(a);
    hB16[(long)n*DD+c]=f2h(b);
  }
}

// final proj: h(fp32) = relu(g @ Wnode)
__global__ __launch_bounds__(256) void k_proj(
    const unsigned short* __restrict__ g16, const float* __restrict__ W,
    float* __restrict__ h, int N)
{
  __shared__ float gl[8][DD];
  int tid = threadIdx.x;
  int ln = tid>>5, c = tid&31;
  int n = blockIdx.x*8 + ln;
  gl[ln][c] = (n<N)? h2f(g16[(long)n*DD+c]) : 0.f;
  __syncthreads();
  float a=0.f;
  #pragma unroll
  for (int k=0;k<DD;k++) a = fmaf(gl[ln][k], W[k*DD+c], a);
  if (n<N) h[(long)n*DD+c] = fmaxf(a, 0.f);
}

__global__ void k_keys(const float* __restrict__ h, unsigned long long* __restrict__ keys, int N){
  int n = blockIdx.x*blockDim.x + threadIdx.x;
  if (n>=N) return;
  const float4* p = reinterpret_cast<const float4*>(h + (long)n*DD);
  float m = -1e38f;
  #pragma unroll
  for (int j=0;j<8;j++){
    float4 v = p[j];
    m = fmaxf(m, fmaxf(fmaxf(v.x,v.y), fmaxf(v.z,v.w)));
  }
  keys[n] = ((unsigned long long)encf(m)<<32) | (unsigned)(~(unsigned)n);
}

// parallel top-8: per-thread register top-8 + 8-round block tournament (keys unique)
__global__ __launch_bounds__(256) void k_ptop(const unsigned long long* __restrict__ keys, int N,
                                              unsigned long long* __restrict__ outk){
  __shared__ unsigned long long red[256];
  int tid = threadIdx.x, b = blockIdx.x, nb = gridDim.x;
  int chunk = (N + nb - 1) / nb;
  int base = b*chunk, end = base+chunk; if (end>N) end=N;
  unsigned long long loc[TOPK];
  #pragma unroll
  for (int i=0;i<TOPK;i++) loc[i]=0ull;
  for (int i=base+tid; i<end; i+=256){
    unsigned long long k = keys[i];
    if (k > loc[TOPK-1]){
      int j = TOPK-1;
      while (j>0 && loc[j-1]<k){ loc[j]=loc[j-1]; j--; }
      loc[j]=k;
    }
  }
  for (int r=0; r<TOPK; r++){
    red[tid] = loc[0];
    __syncthreads();
    for (int s=128; s>0; s>>=1){
      if (tid<s && red[tid+s]>red[tid]) red[tid]=red[tid+s];
      __syncthreads();
    }
    unsigned long long w = red[0];
    if (tid==0) outk[b*TOPK + r] = w;
    if (loc[0]==w){
      #pragma unroll
      for (int j=0;j<TOPK-1;j++) loc[j]=loc[j+1];
      loc[TOPK-1]=0ull;
    }
    __syncthreads();
  }
}

__global__ __launch_bounds__(256) void k_head(
    const float* __restrict__ h, const unsigned long long* __restrict__ sel,
    const float* __restrict__ Wlin, const float* __restrict__ blin,
    const float* __restrict__ W1, const float* __restrict__ b1,
    const float* __restrict__ W2, const float* __restrict__ b2,
    const float* __restrict__ Wc, const float* __restrict__ bc,
    float* __restrict__ out, int N)
{
  __shared__ float xs[TOPK][DD];
  __shared__ float y1[DD], y2[DD], y3[DD];
  int tid=threadIdx.x;
  int r=tid>>5, c=tid&31;
  unsigned node = ~(unsigned)(sel[r] & 0xFFFFFFFFull);
  if (node >= (unsigned)N) node = 0;
  xs[r][c] = h[(long)node*DD + c];
  __syncthreads();
  if (tid<TOPK){
    for (int i=1;i<DD;i++){
      float v=xs[tid][i]; int j=i-1;
      while (j>=0 && xs[tid][j]>v){ xs[tid][j+1]=xs[tid][j]; j--; }
      xs[tid][j+1]=v;
    }
  }
  __syncthreads();
  if (tid<DD){
    float a=blin[tid];
    for (int i=0;i<TOPK*DD;i++) a = fmaf(xs[i>>5][i&31], Wlin[i*DD+tid], a);
    y1[tid] = a>0.f? a : 0.f;
  }
  __syncthreads();
  if (tid<DD){
    float a=b1[tid];
    #pragma unroll
    for (int i=0;i<DD;i++) a = fmaf(y1[i], W1[i*DD+tid], a);
    y2[tid] = a>0.f? a : 0.f;
  }
  __syncthreads();
  if (tid<DD){
    float a=b2[tid];
    #pragma unroll
    for (int i=0;i<DD;i++) a = fmaf(y2[i], W2[i*DD+tid], a);
    y3[tid] = a>0.f? a : 0.f;
  }
  __syncthreads();
  if (tid<2){
    float a=bc[tid];
    #pragma unroll
    for (int i=0;i<DD;i++) a = fmaf(y3[i], Wc[i*2+tid], a);
    out[tid] = a;                       // fp32 output
  }
}

extern "C" void kernel_launch(void* const* d_in, const int* in_sizes, int n_in,
                              void* d_out, int out_size, void* d_ws, size_t ws_size,
                              hipStream_t stream) {
  const int N = in_sizes[0];
  const int E = in_sizes[1];
  const float* tok_emb   = (const float*)d_in[4];
  const float* e_tok_emb = (const float*)d_in[5];
  const float* W_ni  = (const float*)d_in[6];
  const float* W_nj  = (const float*)d_in[7];
  const float* W_fij = (const float*)d_in[8];
  const float* b_e   = (const float*)d_in[9];
  const float* attn  = (const float*)d_in[10];
  const float* W_nd  = (const float*)d_in[11];

  char* p = (char*)d_ws;
  auto alloc = [&](size_t bytes)->char* {
    char* r = p; p += (bytes + 255) & ~(size_t)255; return r;
  };
  // ~131.5 MB total (sde8 aliases h+g16+lbuf, all dead at setup)
  int* iflag = (int*)alloc(256);
  unsigned long long* sel = (unsigned long long*)alloc(256);
  unsigned long long* cand = (unsigned long long*)alloc(256*TOPK*8);
  int* csroff = (int*)alloc((size_t)(N+1)*4);
  unsigned* csr_sd = (unsigned*)alloc((size_t)(E+32)*4);
  float* h = (float*)alloc((size_t)N*DD*4);                     // fp32, final only
  unsigned short* g16  = (unsigned short*)alloc((size_t)N*DD*2);
  unsigned short* lbuf = (unsigned short*)alloc((size_t)(E+32)*2);
  unsigned short* h16  = (unsigned short*)alloc((size_t)N*DD*2);
  unsigned short* hA16 = (unsigned short*)alloc((size_t)N*DD*2);
  unsigned short* hB16 = (unsigned short*)alloc((size_t)N*DD*2);
  unsigned short* ebuf = (unsigned short*)alloc((size_t)(E+32)*DD*2);
  int* cnt    = (int*)hA16;                       // alias: dead until nodeAB
  int* cursor = (int*)hB16;                       // alias: dead until nodeAB
  uint2* sde8 = (uint2*)h;                        // alias: spans h+g16+lbuf (12.8 MB)
  unsigned long long* keys = (unsigned long long*)lbuf;  // alias: lbuf dead after last aggr

  hipLaunchKernelGGL(k_detect, dim3(1), dim3(64), 0, stream, (const int*)d_in[2], iflag);
  hipLaunchKernelGGL(k_zero, dim3((N+255)/256), dim3(256), 0, stream, cnt, cursor, N);
  {
    long total = (long)N*8 + E;
    hipLaunchKernelGGL(k_init, dim3((int)((total+255)/256)), dim3(256), 0, stream,
                       d_in[0], d_in[3], tok_emb, h16, cnt, iflag, N, E);
  }
  hipLaunchKernelGGL(k_scan, dim3(1), dim3(1024), 0, stream, cnt, csroff, N, E);
  {
    int npr = (N + NXCD - 1) / NXCD;
    int nchunk = (E + SCHUNK - 1) / SCHUNK;
    hipLaunchKernelGGL(k_scatter, dim3(NXCD*nchunk), dim3(256), 0, stream,
                       d_in[2], d_in[3], csroff, cursor, sde8, iflag, E, npr);
  }
  hipLaunchKernelGGL(k_fill, dim3((int)(((long)E*4+255)/256)), dim3(256), 0, stream,
                     sde8, d_in[1], e_tok_emb, csr_sd, ebuf, iflag, E);

  int nb_node = (N+7)/8;
  int ntiles = (E+15)/16;
  hipLaunchKernelGGL(k_nodeAB, dim3(nb_node), dim3(256), 0, stream,
                     h16, W_ni, W_nj, hA16, hB16, N);
  for (int l=0; l<NLAYERS; l++){
    const float* Wf  = W_fij + (size_t)l*DD*DD;
    const float* bl  = b_e   + (size_t)l*DD;
    const float* at  = attn  + (size_t)l*DD;
    const float* Wnd = W_nd  + (size_t)l*DD*DD;
    hipLaunchKernelGGL(k_edge, dim3(2048), dim3(256), 0, stream,
                       ebuf, hA16, hB16, csr_sd, Wf, bl, at, lbuf, ntiles,
                       (l < NLAYERS-1) ? 1 : 0);
    hipLaunchKernelGGL(k_aggr, dim3(nb_node), dim3(256), 0, stream,
                       h16, lbuf, csroff, csr_sd, g16, N);
    if (l < NLAYERS-1){
      const float* WnA = W_ni + (size_t)(l+1)*DD*DD;
      const float* WnB = W_nj + (size_t)(l+1)*DD*DD;
      hipLaunchKernelGGL(k_pnAB, dim3(nb_node), dim3(256), 0, stream,
                         g16, Wnd, WnA, WnB, h16, hA16, hB16, N);
    } else {
      hipLaunchKernelGGL(k_proj, dim3(nb_node), dim3(256), 0, stream,
                         g16, Wnd, h, N);
    }
  }

  hipLaunchKernelGGL(k_keys, dim3((N+255)/256), dim3(256), 0, stream, h, keys, N);
  hipLaunchKernelGGL(k_ptop, dim3(256), dim3(256), 0, stream, keys, N, cand);
  hipLaunchKernelGGL(k_ptop, dim3(1), dim3(256), 0, stream, cand, 256*TOPK, sel);
  hipLaunchKernelGGL(k_head, dim3(1), dim3(256), 0, stream,
                     h, sel,
                     (const float*)d_in[12], (const float*)d_in[13],
                     (const float*)d_in[14], (const float*)d_in[15],
                     (const float*)d_in[16], (const float*)d_in[17],
                     (const float*)d_in[18], (const float*)d_in[19],
                     (float*)d_out, N);
}

// Round 2
// 1376.509 us; speedup vs baseline: 1.0318x; 1.0198x over previous
//
#include <hip/hip_runtime.h>
#include <hip/hip_fp16.h>

#define DD 32
#define NLAYERS 8
#define TOPK 8
#define NPB 256      // nodes per bucket (power of 2 -> bucket = dst>>8)
#define HNB 1024     // max buckets supported (N <= 262144)
#define BCH 4096     // edges per phase-1 block
#define P2CAP 12288  // phase-2 LDS record capacity (96 KB; bucket mean ~8192, sigma ~90)

typedef _Float16 half8 __attribute__((ext_vector_type(8)));
typedef float f32x4 __attribute__((ext_vector_type(4)));

__device__ __forceinline__ unsigned encf(float x){ unsigned u=__float_as_uint(x); return (u&0x80000000u)? ~u : (u|0x80000000u); }
__device__ __forceinline__ unsigned short f2h(float f){ return __half_as_ushort(__float2half(f)); }
__device__ __forceinline__ float h2f(unsigned short u){ return __half2float(__ushort_as_half(u)); }
__device__ __forceinline__ float4 up4(uint2 u){
  float4 r;
  r.x=h2f((unsigned short)(u.x&0xFFFFu)); r.y=h2f((unsigned short)(u.x>>16));
  r.z=h2f((unsigned short)(u.y&0xFFFFu)); r.w=h2f((unsigned short)(u.y>>16));
  return r;
}
union HU { uint2 u; half8 h; };   // b-fragment reinterpret (8 fp16 = 4 VGPRs... 2x uint2)
union HU4 { uint4 u; half8 h; };
__device__ __forceinline__ int gidx(const void* p, long i, int i64){
  return i64 ? (int)((const long long*)p)[i] : ((const int*)p)[i];
}

__global__ void k_detect(const int* __restrict__ srcw, int* __restrict__ iflag){
  if (threadIdx.x==0 && blockIdx.x==0){
    int allz = 1;
    for (int k=1;k<32;k+=2) if (srcw[k]!=0) allz = 0;
    *iflag = allz;
  }
}

__global__ void k_zero(int* cnt, int N){
  int n = blockIdx.x*blockDim.x + threadIdx.x;
  if (n<N) cnt[n]=0;
}

// h16 = fp16(relu(tok_emb[h_tok])) ; in-degree histogram
__global__ void k_init(const void* __restrict__ h_tok, const void* __restrict__ dstv,
                       const float* __restrict__ tok_emb,
                       unsigned short* __restrict__ h16, int* __restrict__ cnt,
                       const int* __restrict__ iflag, int N, int E)
{
  int i64 = *iflag;
  long idx = (long)blockIdx.x*blockDim.x + threadIdx.x;
  if (idx < (long)N*8){
    int n=(int)(idx>>3), q=(int)(idx&7);
    int t = gidx(h_tok, n, i64);
    float4 v = reinterpret_cast<const float4*>(tok_emb)[t*8+q];
    uint2 o;
    o.x = (unsigned)f2h(fmaxf(v.x,0.f)) | ((unsigned)f2h(fmaxf(v.y,0.f))<<16);
    o.y = (unsigned)f2h(fmaxf(v.z,0.f)) | ((unsigned)f2h(fmaxf(v.w,0.f))<<16);
    reinterpret_cast<uint2*>(h16)[(long)n*8+q] = o;
    return;
  }
  idx -= (long)N*8;
  if (idx < E){
    atomicAdd(&cnt[gidx(dstv, idx, i64)], 1);
  }
}

// single-block exclusive scan of in-degrees -> csr_off (wave shuffle-scan)
__global__ __launch_bounds__(1024) void k_scan(const int* __restrict__ cnt, int* __restrict__ off,
                                               int N, int E){
  __shared__ int wsum[16];
  __shared__ int carry_s;
  int tid = threadIdx.x;
  int lane = tid & 63, w = tid >> 6;
  if (tid==0) carry_s = 0;
  __syncthreads();
  for (int base=0; base<N; base+=1024){
    int v = (base+tid<N)? cnt[base+tid] : 0;
    int x = v;
    #pragma unroll
    for (int d=1; d<64; d<<=1){
      int t = __shfl_up(x, d, 64);
      if (lane>=d) x += t;
    }
    if (lane==63) wsum[w] = x;
    __syncthreads();
    if (w==0 && lane<16){
      int y = wsum[lane];
      #pragma unroll
      for (int d=1; d<16; d<<=1){
        int t = __shfl_up(y, d, 64);
        if (lane>=d) y += t;
      }
      wsum[lane] = y;
    }
    __syncthreads();
    int cl = carry_s;
    int wb = (w>0)? wsum[w-1] : 0;
    int tot = wsum[15];
    if (base+tid<N) off[base+tid] = cl + x + wb - v;
    __syncthreads();
    if (tid==0) carry_s = cl + tot;
    __syncthreads();
  }
  if (tid==0) off[N] = E;
}

// per-bucket global cursor init: gcur[b] = off[min(b*NPB, N)]
__global__ void k_bcur(const int* __restrict__ off, int* __restrict__ gcur, int N, int NB){
  int b = blockIdx.x*blockDim.x + threadIdx.x;
  if (b < NB){
    int lo = b*NPB; if (lo > N) lo = N;
    gcur[b] = off[lo];
  }
}

// PHASE 1: bucket edges by dst>>8 into btmp (unordered within bucket).
// Per block: LDS histogram -> one global atomicAdd per bucket reserves a
// contiguous run -> scatter into runs of ~BCH/NB contiguous records. All
// reads coalesced; writes are short contiguous runs (write-amp ~1.4x) --
// no dependence on cross-XCD L2 merging of random 8 B stores.
__global__ __launch_bounds__(256) void k_bucket(
    const void* __restrict__ srcv, const void* __restrict__ dstv,
    int* __restrict__ gcur, uint2* __restrict__ btmp,
    const int* __restrict__ iflag, int E, int NB)
{
  __shared__ int hist[HNB];
  __shared__ int cbase[HNB];
  int i64 = *iflag;
  int tid = threadIdx.x;
  long base = (long)blockIdx.x * BCH;
  long rem = (long)E - base;
  int nloc = (rem < BCH) ? (int)rem : BCH;
  if (nloc <= 0) return;
  for (int i = tid; i < NB; i += 256) hist[i] = 0;
  __syncthreads();
  int dl[BCH/256];
  #pragma unroll
  for (int k = 0; k < BCH/256; k++){
    int t = tid + k*256;
    dl[k] = -1;
    if (t < nloc){
      int d = gidx(dstv, base + t, i64);
      dl[k] = d;
      atomicAdd(&hist[d>>8], 1);
    }
  }
  __syncthreads();
  for (int i = tid; i < NB; i += 256){
    int hv = hist[i];
    cbase[i] = hv ? atomicAdd(&gcur[i], hv) : 0;
    hist[i] = 0;                      // reuse as local cursor
  }
  __syncthreads();
  #pragma unroll
  for (int k = 0; k < BCH/256; k++){
    int t = tid + k*256;
    if (t < nloc){
      int d = dl[k];
      int s = gidx(srcv, base + t, i64);
      int b = d>>8;
      int slot = cbase[b] + atomicAdd(&hist[b], 1);
      uint2 r; r.x = ((unsigned)d<<16) | (unsigned)s; r.y = (unsigned)(base + t);
      btmp[slot] = r;
    }
  }
}

// PHASE 2: one block per bucket. Final CSR positions of bucket b are exactly
// [off[lo], off[hi]) -- load bucket (coalesced), rank via LDS cursors into a
// 96 KB LDS staging array, write out linearly (coalesced). Overflow bucket
// (>P2CAP, ~45 sigma above mean) falls back to direct out-of-place scatter.
__global__ __launch_bounds__(256) void k_bsort(
    const int* __restrict__ off, const uint2* __restrict__ btmp,
    uint2* __restrict__ sde8, int N)
{
  __shared__ int lcur[NPB];
  __shared__ uint2 lrec[P2CAP];
  int bkt = blockIdx.x;
  int lo = bkt*NPB;
  int hi = lo + NPB; if (hi > N) hi = N;
  int base = off[lo], endp = off[hi];
  int sz = endp - base;
  int tid = threadIdx.x;
  for (int i = tid; i < NPB; i += 256) lcur[i] = 0;
  __syncthreads();
  if (sz <= P2CAP){
    for (int i = tid; i < sz; i += 256){
      uint2 r = btmp[base + i];
      int d = (int)(r.x >> 16);
      int local = off[d] - base + atomicAdd(&lcur[d - lo], 1);
      lrec[local] = r;
    }
    __syncthreads();
    for (int i = tid; i < sz; i += 256)
      sde8[base + i] = lrec[i];
  } else {
    for (int i = tid; i < sz; i += 256){
      uint2 r = btmp[base + i];
      int d = (int)(r.x >> 16);
      int pos = off[d] + atomicAdd(&lcur[d - lo], 1);
      sde8[pos] = r;
    }
  }
}

// stream sde8: emit csr_sd sequentially + fill ebuf (fp16) from L1-resident e_emb table
__global__ void k_fill(const uint2* __restrict__ sde8, const void* __restrict__ e_tok,
                       const float* __restrict__ e_emb,
                       unsigned* __restrict__ csr_sd, unsigned short* __restrict__ ebuf,
                       const int* __restrict__ iflag, int E){
  int i64 = *iflag;
  long idx = (long)blockIdx.x*blockDim.x + threadIdx.x;
  if (idx >= (long)E*4) return;
  int pos = (int)(idx>>2), j = (int)(idx&3);
  uint2 r = sde8[pos];
  if (j==0) csr_sd[pos] = r.x;
  int t = gidx(e_tok, (int)r.y, i64);
  const float4* sp = reinterpret_cast<const float4*>(e_emb + t*DD) + j*2;
  float4 x = sp[0], y = sp[1];
  uint4 ov;
  ov.x = (unsigned)f2h(x.x) | ((unsigned)f2h(x.y)<<16);
  ov.y = (unsigned)f2h(x.z) | ((unsigned)f2h(x.w)<<16);
  ov.z = (unsigned)f2h(y.x) | ((unsigned)f2h(y.y)<<16);
  ov.w = (unsigned)f2h(y.z) | ((unsigned)f2h(y.w)<<16);
  reinterpret_cast<uint4*>(ebuf)[(long)pos*4+j] = ov;
}

// hA16=h16@Wni, hB16=h16@Wnj   (first layer only)
__global__ __launch_bounds__(256) void k_nodeAB(
    const unsigned short* __restrict__ h16,
    const float* __restrict__ WA, const float* __restrict__ WB,
    unsigned short* __restrict__ hA16, unsigned short* __restrict__ hB16, int N)
{
  __shared__ float hl[8][DD];
  int tid = threadIdx.x;
  int ln = tid>>5, c = tid&31;
  int n = blockIdx.x*8 + ln;
  hl[ln][c] = (n<N)? h2f(h16[(long)n*DD+c]) : 0.f;
  __syncthreads();
  float a=0.f,b=0.f;
  #pragma unroll
  for (int k=0;k<DD;k++){
    float v = hl[ln][k];
    a = fmaf(v, WA[k*DD+c], a);
    b = fmaf(v, WB[k*DD+c], b);
  }
  if (n<N){ hA16[(long)n*DD+c]=f2h(a); hB16[(long)n*DD+c]=f2h(b); }
}

// MFMA fp16 edge kernel, SOFTWARE-PIPELINED depth 2: one wave = 16 edges.
// D[m][n=edge]=Wf^T·e^T; f=leaky(D+hA[src]+hB[dst]+b); ebuf<-f; lbuf=exp(f·attn)
__global__ __launch_bounds__(256) void k_edge(
    unsigned short* __restrict__ ebuf,
    const unsigned short* __restrict__ hA16, const unsigned short* __restrict__ hB16,
    const unsigned* __restrict__ csr_sd,
    const float* __restrict__ Wf, const float* __restrict__ bvec,
    const float* __restrict__ attn,
    unsigned short* __restrict__ lbuf, int ntiles, int writef)
{
  int lane = threadIdx.x & 63;
  int wid = (blockIdx.x*256 + threadIdx.x) >> 6;
  int nw  = (gridDim.x*256) >> 6;
  int m = lane & 15, q = lane >> 4;
  half8 a0, a1;
  #pragma unroll
  for (int j=0;j<8;j++){
    a0[j] = (_Float16)Wf[(q*8+j)*DD + m];
    a1[j] = (_Float16)Wf[(q*8+j)*DD + 16 + m];
  }
  float4 blo = *reinterpret_cast<const float4*>(bvec + q*4);
  float4 bhi = *reinterpret_cast<const float4*>(bvec + 16 + q*4);
  float4 alo = *reinterpret_cast<const float4*>(attn + q*4);
  float4 ahi = *reinterpret_cast<const float4*>(attn + 16 + q*4);
  f32x4 zero = {0.f,0.f,0.f,0.f};
  // depth-2 preamble: tile0 = fully loaded; tile1 = sd+b loaded
  HU4 b0; b0.u = make_uint4(0,0,0,0);
  HU4 b1; b1.u = make_uint4(0,0,0,0);
  unsigned sd0 = 0, sd1 = 0;
  uint2 gA0_0={0,0}, gA1_0={0,0}, gB0_0={0,0}, gB1_0={0,0};
  if (wid < ntiles){
    long e0 = (long)wid*16 + m;
    sd0 = csr_sd[e0];
    b0.u = *reinterpret_cast<const uint4*>(ebuf + e0*DD + q*8);
    unsigned s = sd0 & 0xFFFFu, d = sd0 >> 16;
    const uint2* pA = reinterpret_cast<const uint2*>(hA16 + (long)s*DD);
    const uint2* pB = reinterpret_cast<const uint2*>(hB16 + (long)d*DD);
    gA0_0=pA[q]; gA1_0=pA[4+q]; gB0_0=pB[q]; gB1_0=pB[4+q];
  }
  if (wid + nw < ntiles){
    long e1 = (long)(wid+nw)*16 + m;
    sd1 = csr_sd[e1];
    b1.u = *reinterpret_cast<const uint4*>(ebuf + e1*DD + q*8);
  }
  for (int t = wid; t < ntiles; t += nw){
    int t1 = t + nw, t2 = t + 2*nw;
    // 1) issue sd/b for tile t+2nw (fully independent)
    unsigned sd2 = 0; HU4 b2; b2.u = make_uint4(0,0,0,0);
    if (t2 < ntiles){
      long e2 = (long)t2*16 + m;
      sd2 = csr_sd[e2];
      b2.u = *reinterpret_cast<const uint4*>(ebuf + e2*DD + q*8);
    }
    // 2) issue gathers for tile t+nw (dep: sd1, resident since last iteration)
    uint2 gA0_1={0,0}, gA1_1={0,0}, gB0_1={0,0}, gB1_1={0,0};
    if (t1 < ntiles){
      unsigned s = sd1 & 0xFFFFu, d = sd1 >> 16;
      const uint2* pA = reinterpret_cast<const uint2*>(hA16 + (long)s*DD);
      const uint2* pB = reinterpret_cast<const uint2*>(hB16 + (long)d*DD);
      gA0_1=pA[q]; gA1_1=pA[4+q]; gB0_1=pB[q]; gB1_1=pB[4+q];
    }
    // 3) MFMA on current tile (b0 resident)
    f32x4 d0 = __builtin_amdgcn_mfma_f32_16x16x32_f16(a0, b0.h, zero, 0,0,0);
    f32x4 d1 = __builtin_amdgcn_mfma_f32_16x16x32_f16(a1, b0.h, zero, 0,0,0);
    // 4) epilogue with current gathers (issued a full iteration ago)
    long tbase = (long)t*16;
    long edge = tbase + m;
    float4 A0 = up4(gA0_0), A1 = up4(gA1_0);
    float4 B0 = up4(gB0_0), B1 = up4(gB1_0);
    float f00 = d0[0]+A0.x+B0.x+blo.x, f01 = d0[1]+A0.y+B0.y+blo.y;
    float f02 = d0[2]+A0.z+B0.z+blo.z, f03 = d0[3]+A0.w+B0.w+blo.w;
    float f10 = d1[0]+A1.x+B1.x+bhi.x, f11 = d1[1]+A1.y+B1.y+bhi.y;
    float f12 = d1[2]+A1.z+B1.z+bhi.z, f13 = d1[3]+A1.w+B1.w+bhi.w;
    f00 = (f00>0.f)?f00:0.01f*f00; f01 = (f01>0.f)?f01:0.01f*f01;
    f02 = (f02>0.f)?f02:0.01f*f02; f03 = (f03>0.f)?f03:0.01f*f03;
    f10 = (f10>0.f)?f10:0.01f*f10; f11 = (f11>0.f)?f11:0.01f*f11;
    f12 = (f12>0.f)?f12:0.01f*f12; f13 = (f13>0.f)?f13:0.01f*f13;
    if (writef){
      uint2 w0, w1;
      w0.x = (unsigned)f2h(f00) | ((unsigned)f2h(f01)<<16);
      w0.y = (unsigned)f2h(f02) | ((unsigned)f2h(f03)<<16);
      w1.x = (unsigned)f2h(f10) | ((unsigned)f2h(f11)<<16);
      w1.y = (unsigned)f2h(f12) | ((unsigned)f2h(f13)<<16);
      *reinterpret_cast<uint2*>(ebuf + edge*DD + q*4) = w0;
      *reinterpret_cast<uint2*>(ebuf + edge*DD + 16 + q*4) = w1;
    }
    float l = f00*alo.x + f01*alo.y + f02*alo.z + f03*alo.w
            + f10*ahi.x + f11*ahi.y + f12*ahi.z + f13*ahi.w;
    l += __shfl_xor(l, 16, 64);
    l += __shfl_xor(l, 32, 64);
    if (lane < 16){
      float lc = fminf(fmaxf(l, -15.f), 10.5f);
      lbuf[tbase + lane] = f2h(__expf(lc));   // max-free softmax weight
    }
    // rotate pipeline
    sd0 = sd1; b0 = b1;
    gA0_0=gA0_1; gA1_0=gA1_1; gB0_0=gB0_1; gB1_0=gB1_1;
    sd1 = sd2; b1 = b2;
  }
}

// per dst node (32 lanes, CSR): g16 = fp16( (sum ex*h16[src]) / (sum ex) )
__global__ __launch_bounds__(256) void k_aggr(
    const unsigned short* __restrict__ h16, const unsigned short* __restrict__ lbuf,
    const int* __restrict__ off, const unsigned* __restrict__ csr_sd,
    unsigned short* __restrict__ g16, int N)
{
  int tid=threadIdx.x;
  int n = blockIdx.x*8 + (tid>>5);
  int c = tid&31;
  if (n>=N) return;
  int o0 = off[n], o1 = off[n+1];
  float num=0.f, den=0.f;
  for (int i=o0;i<o1;i++){
    float ex = h2f(lbuf[i]);
    unsigned s = csr_sd[i] & 0xFFFFu;
    num = fmaf(ex, h2f(h16[(long)s*DD+c]), num);
    den += ex;
  }
  g16[(long)n*DD+c] = f2h((den>0.f) ? num/den : 0.f);
}

// fused proj + next-layer nodeAB: h16 = relu(g@Wnd); hA16 = h@WA; hB16 = h@WB
__global__ __launch_bounds__(256) void k_pnAB(
    const unsigned short* __restrict__ g16, const float* __restrict__ Wnd,
    const float* __restrict__ WA, const float* __restrict__ WB,
    unsigned short* __restrict__ h16,
    unsigned short* __restrict__ hA16, unsigned short* __restrict__ hB16, int N)
{
  __shared__ float gl[8][DD];
  __shared__ float tl[8][DD];
  int tid = threadIdx.x;
  int ln = tid>>5, c = tid&31;
  int n = blockIdx.x*8 + ln;
  gl[ln][c] = (n<N)? h2f(g16[(long)n*DD+c]) : 0.f;
  __syncthreads();
  float t=0.f;
  #pragma unroll
  for (int k=0;k<DD;k++) t = fmaf(gl[ln][k], Wnd[k*DD+c], t);
  t = fmaxf(t, 0.f);
  tl[ln][c] = t;
  __syncthreads();
  float a=0.f,b=0.f;
  #pragma unroll
  for (int k=0;k<DD;k++){
    float v = tl[ln][k];
    a = fmaf(v, WA[k*DD+c], a);
    b = fmaf(v, WB[k*DD+c], b);
  }
  if (n<N){
    h16[(long)n*DD+c]=f2h(t);
    hA16[(long)n*DD+c]=f2h(a);
    hB16[(long)n*DD+c]=f2h(b);
  }
}

// final proj: h(fp32) = relu(g @ Wnode)
__global__ __launch_bounds__(256) void k_proj(
    const unsigned short* __restrict__ g16, const float* __restrict__ W,
    float* __restrict__ h, int N)
{
  __shared__ float gl[8][DD];
  int tid = threadIdx.x;
  int ln = tid>>5, c = tid&31;
  int n = blockIdx.x*8 + ln;
  gl[ln][c] = (n<N)? h2f(g16[(long)n*DD+c]) : 0.f;
  __syncthreads();
  float a=0.f;
  #pragma unroll
  for (int k=0;k<DD;k++) a = fmaf(gl[ln][k], W[k*DD+c], a);
  if (n<N) h[(long)n*DD+c] = fmaxf(a, 0.f);
}

__global__ void k_keys(const float* __restrict__ h, unsigned long long* __restrict__ keys, int N){
  int n = blockIdx.x*blockDim.x + threadIdx.x;
  if (n>=N) return;
  const float4* p = reinterpret_cast<const float4*>(h + (long)n*DD);
  float m = -1e38f;
  #pragma unroll
  for (int j=0;j<8;j++){
    float4 v = p[j];
    m = fmaxf(m, fmaxf(fmaxf(v.x,v.y), fmaxf(v.z,v.w)));
  }
  keys[n] = ((unsigned long long)encf(m)<<32) | (unsigned)(~(unsigned)n);
}

// parallel top-8: per-thread register top-8 + 8-round block tournament (keys unique)
__global__ __launch_bounds__(256) void k_ptop(const unsigned long long* __restrict__ keys, int N,
                                              unsigned long long* __restrict__ outk){
  __shared__ unsigned long long red[256];
  int tid = threadIdx.x, b = blockIdx.x, nb = gridDim.x;
  int chunk = (N + nb - 1) / nb;
  int base = b*chunk, end = base+chunk; if (end>N) end=N;
  unsigned long long loc[TOPK];
  #pragma unroll
  for (int i=0;i<TOPK;i++) loc[i]=0ull;
  for (int i=base+tid; i<end; i+=256){
    unsigned long long k = keys[i];
    if (k > loc[TOPK-1]){
      int j = TOPK-1;
      while (j>0 && loc[j-1]<k){ loc[j]=loc[j-1]; j--; }
      loc[j]=k;
    }
  }
  for (int r=0; r<TOPK; r++){
    red[tid] = loc[0];
    __syncthreads();
    for (int s=128; s>0; s>>=1){
      if (tid<s && red[tid+s]>red[tid]) red[tid]=red[tid+s];
      __syncthreads();
    }
    unsigned long long w = red[0];
    if (tid==0) outk[b*TOPK + r] = w;
    if (loc[0]==w){
      #pragma unroll
      for (int j=0;j<TOPK-1;j++) loc[j]=loc[j+1];
      loc[TOPK-1]=0ull;
    }
    __syncthreads();
  }
}

__global__ __launch_bounds__(256) void k_head(
    const float* __restrict__ h, const unsigned long long* __restrict__ sel,
    const float* __restrict__ Wlin, const float* __restrict__ blin,
    const float* __restrict__ W1, const float* __restrict__ b1,
    const float* __restrict__ W2, const float* __restrict__ b2,
    const float* __restrict__ Wc, const float* __restrict__ bc,
    float* __restrict__ out, int N)
{
  __shared__ float xs[TOPK][DD];
  __shared__ float y1[DD], y2[DD], y3[DD];
  int tid=threadIdx.x;
  int r=tid>>5, c=tid&31;
  unsigned node = ~(unsigned)(sel[r] & 0xFFFFFFFFull);
  if (node >= (unsigned)N) node = 0;
  xs[r][c] = h[(long)node*DD + c];
  __syncthreads();
  if (tid<TOPK){
    for (int i=1;i<DD;i++){
      float v=xs[tid][i]; int j=i-1;
      while (j>=0 && xs[tid][j]>v){ xs[tid][j+1]=xs[tid][j]; j--; }
      xs[tid][j+1]=v;
    }
  }
  __syncthreads();
  if (tid<DD){
    float a=blin[tid];
    for (int i=0;i<TOPK*DD;i++) a = fmaf(xs[i>>5][i&31], Wlin[i*DD+tid], a);
    y1[tid] = a>0.f? a : 0.f;
  }
  __syncthreads();
  if (tid<DD){
    float a=b1[tid];
    #pragma unroll
    for (int i=0;i<DD;i++) a = fmaf(y1[i], W1[i*DD+tid], a);
    y2[tid] = a>0.f? a : 0.f;
  }
  __syncthreads();
  if (tid<DD){
    float a=b2[tid];
    #pragma unroll
    for (int i=0;i<DD;i++) a = fmaf(y2[i], W2[i*DD+tid], a);
    y3[tid] = a>0.f? a : 0.f;
  }
  __syncthreads();
  if (tid<2){
    float a=bc[tid];
    #pragma unroll
    for (int i=0;i<DD;i++) a = fmaf(y3[i], Wc[i*2+tid], a);
    out[tid] = a;                       // fp32 output
  }
}

extern "C" void kernel_launch(void* const* d_in, const int* in_sizes, int n_in,
                              void* d_out, int out_size, void* d_ws, size_t ws_size,
                              hipStream_t stream) {
  const int N = in_sizes[0];
  const int E = in_sizes[1];
  const float* tok_emb   = (const float*)d_in[4];
  const float* e_tok_emb = (const float*)d_in[5];
  const float* W_ni  = (const float*)d_in[6];
  const float* W_nj  = (const float*)d_in[7];
  const float* W_fij = (const float*)d_in[8];
  const float* b_e   = (const float*)d_in[9];
  const float* attn  = (const float*)d_in[10];
  const float* W_nd  = (const float*)d_in[11];

  char* p = (char*)d_ws;
  auto alloc = [&](size_t bytes)->char* {
    char* r = p; p += (bytes + 255) & ~(size_t)255; return r;
  };
  // ~131.5 MB total (sde8 aliases h+g16+lbuf; btmp aliases ebuf; all dead at setup)
  int* iflag = (int*)alloc(256);
  unsigned long long* sel = (unsigned long long*)alloc(256);
  unsigned long long* cand = (unsigned long long*)alloc(256*TOPK*8);
  int* gcur = (int*)alloc(HNB*4);
  int* csroff = (int*)alloc((size_t)(N+1)*4);
  unsigned* csr_sd = (unsigned*)alloc((size_t)(E+32)*4);
  float* h = (float*)alloc((size_t)N*DD*4);                     // fp32, final only
  unsigned short* g16  = (unsigned short*)alloc((size_t)N*DD*2);
  unsigned short* lbuf = (unsigned short*)alloc((size_t)(E+32)*2);
  unsigned short* h16  = (unsigned short*)alloc((size_t)N*DD*2);
  unsigned short* hA16 = (unsigned short*)alloc((size_t)N*DD*2);
  unsigned short* hB16 = (unsigned short*)alloc((size_t)N*DD*2);
  unsigned short* ebuf = (unsigned short*)alloc((size_t)(E+32)*DD*2);
  int* cnt    = (int*)hA16;                       // alias: dead until nodeAB
  uint2* sde8 = (uint2*)h;                        // alias: spans h+g16+lbuf (12.8 MB)
  uint2* btmp = (uint2*)ebuf;                     // alias: ebuf dead until k_fill
  unsigned long long* keys = (unsigned long long*)lbuf;  // alias: lbuf dead after last aggr

  const int NB = (N + NPB - 1) / NPB;             // buckets (196 @ N=50k)

  hipLaunchKernelGGL(k_detect, dim3(1), dim3(64), 0, stream, (const int*)d_in[2], iflag);
  hipLaunchKernelGGL(k_zero, dim3((N+255)/256), dim3(256), 0, stream, cnt, N);
  {
    long total = (long)N*8 + E;
    hipLaunchKernelGGL(k_init, dim3((int)((total+255)/256)), dim3(256), 0, stream,
                       d_in[0], d_in[3], tok_emb, h16, cnt, iflag, N, E);
  }
  hipLaunchKernelGGL(k_scan, dim3(1), dim3(1024), 0, stream, cnt, csroff, N, E);
  hipLaunchKernelGGL(k_bcur, dim3((NB+255)/256), dim3(256), 0, stream, csroff, gcur, N, NB);
  hipLaunchKernelGGL(k_bucket, dim3((E+BCH-1)/BCH), dim3(256), 0, stream,
                     d_in[2], d_in[3], gcur, btmp, iflag, E, NB);
  hipLaunchKernelGGL(k_bsort, dim3(NB), dim3(256), 0, stream, csroff, btmp, sde8, N);
  hipLaunchKernelGGL(k_fill, dim3((int)(((long)E*4+255)/256)), dim3(256), 0, stream,
                     sde8, d_in[1], e_tok_emb, csr_sd, ebuf, iflag, E);

  int nb_node = (N+7)/8;
  int ntiles = (E+15)/16;
  hipLaunchKernelGGL(k_nodeAB, dim3(nb_node), dim3(256), 0, stream,
                     h16, W_ni, W_nj, hA16, hB16, N);
  for (int l=0; l<NLAYERS; l++){
    const float* Wf  = W_fij + (size_t)l*DD*DD;
    const float* bl  = b_e   + (size_t)l*DD;
    const float* at  = attn  + (size_t)l*DD;
    const float* Wnd = W_nd  + (size_t)l*DD*DD;
    hipLaunchKernelGGL(k_edge, dim3(2048), dim3(256), 0, stream,
                       ebuf, hA16, hB16, csr_sd, Wf, bl, at, lbuf, ntiles,
                       (l < NLAYERS-1) ? 1 : 0);
    hipLaunchKernelGGL(k_aggr, dim3(nb_node), dim3(256), 0, stream,
                       h16, lbuf, csroff, csr_sd, g16, N);
    if (l < NLAYERS-1){
      const float* WnA = W_ni + (size_t)(l+1)*DD*DD;
      const float* WnB = W_nj + (size_t)(l+1)*DD*DD;
      hipLaunchKernelGGL(k_pnAB, dim3(nb_node), dim3(256), 0, stream,
                         g16, Wnd, WnA, WnB, h16, hA16, hB16, N);
    } else {
      hipLaunchKernelGGL(k_proj, dim3(nb_node), dim3(256), 0, stream,
                         g16, Wnd, h, N);
    }
  }

  hipLaunchKernelGGL(k_keys, dim3((N+255)/256), dim3(256), 0, stream, h, keys, N);
  hipLaunchKernelGGL(k_ptop, dim3(256), dim3(256), 0, stream, keys, N, cand);
  hipLaunchKernelGGL(k_ptop, dim3(1), dim3(256), 0, stream, cand, 256*TOPK, sel);
  hipLaunchKernelGGL(k_head, dim3(1), dim3(256), 0, stream,
                     h, sel,
                     (const float*)d_in[12], (const float*)d_in[13],
                     (const float*)d_in[14], (const float*)d_in[15],
                     (const float*)d_in[16], (const float*)d_in[17],
                     (const float*)d_in[18], (const float*)d_in[19],
                     (float*)d_out, N);
}

// Round 3
// 1273.609 us; speedup vs baseline: 1.1151x; 1.0808x over previous
//
#include <hip/hip_runtime.h>
#include <hip/hip_fp16.h>

#define DD 32
#define NLAYERS 8
#define TOPK 8
#define NPB 256      // nodes per bucket (power of 2 -> bucket = dst>>8)
#define HNB 1024     // max buckets supported (N <= 262144)
#define BCH 4096     // edges per phase-1 block
#define P2CAP 12288  // phase-2 LDS record capacity (96 KB; bucket mean ~8192, sigma ~90)

typedef _Float16 half8 __attribute__((ext_vector_type(8)));
typedef float f32x4 __attribute__((ext_vector_type(4)));

__device__ __forceinline__ unsigned encf(float x){ unsigned u=__float_as_uint(x); return (u&0x80000000u)? ~u : (u|0x80000000u); }
__device__ __forceinline__ unsigned short f2h(float f){ return __half_as_ushort(__float2half(f)); }
__device__ __forceinline__ float h2f(unsigned short u){ return __half2float(__ushort_as_half(u)); }
__device__ __forceinline__ float4 up4(uint2 u){
  float4 r;
  r.x=h2f((unsigned short)(u.x&0xFFFFu)); r.y=h2f((unsigned short)(u.x>>16));
  r.z=h2f((unsigned short)(u.y&0xFFFFu)); r.w=h2f((unsigned short)(u.y>>16));
  return r;
}
union HU { uint2 u; half8 h; };   // b-fragment reinterpret (8 fp16 = 4 VGPRs... 2x uint2)
union HU4 { uint4 u; half8 h; };
__device__ __forceinline__ int gidx(const void* p, long i, int i64){
  return i64 ? (int)((const long long*)p)[i] : ((const int*)p)[i];
}

// also zeroes bcnt (bucket histogram) to avoid an extra launch
__global__ __launch_bounds__(1024) void k_detect(const int* __restrict__ srcw,
                                                 int* __restrict__ iflag,
                                                 int* __restrict__ bcnt){
  int tid = threadIdx.x;
  for (int i=tid;i<HNB;i+=1024) bcnt[i]=0;
  if (tid==0){
    int allz = 1;
    for (int k=1;k<32;k+=2) if (srcw[k]!=0) allz = 0;
    *iflag = allz;
  }
}

// h16 = fp16(relu(tok_emb[h_tok]))   (histogram removed: was 1.6M device-scope
// atomics = 52.9 MB of memory-side RMW traffic, 70 us)
__global__ void k_init(const void* __restrict__ h_tok,
                       const float* __restrict__ tok_emb,
                       unsigned short* __restrict__ h16,
                       const int* __restrict__ iflag, int N)
{
  int i64 = *iflag;
  long idx = (long)blockIdx.x*blockDim.x + threadIdx.x;
  if (idx >= (long)N*8) return;
  int n=(int)(idx>>3), q=(int)(idx&7);
  int t = gidx(h_tok, n, i64);
  float4 v = reinterpret_cast<const float4*>(tok_emb)[t*8+q];
  uint2 o;
  o.x = (unsigned)f2h(fmaxf(v.x,0.f)) | ((unsigned)f2h(fmaxf(v.y,0.f))<<16);
  o.y = (unsigned)f2h(fmaxf(v.z,0.f)) | ((unsigned)f2h(fmaxf(v.w,0.f))<<16);
  reinterpret_cast<uint2*>(h16)[(long)n*8+q] = o;
}

// bucket-level histogram: LDS bins + 1 global atomic per (block,bin)
// (77k atomics total vs 1.6M node-level)
__global__ __launch_bounds__(256) void k_hist(
    const void* __restrict__ dstv, int* __restrict__ bcnt,
    const int* __restrict__ iflag, int E, int NB)
{
  __shared__ int bins[HNB];
  int i64 = *iflag;
  int tid = threadIdx.x;
  for (int i=tid;i<NB;i+=256) bins[i]=0;
  __syncthreads();
  long base = (long)blockIdx.x * BCH;
  long rem = (long)E - base;
  int nloc = (rem < BCH) ? (int)rem : BCH;
  for (int t=tid; t<nloc; t+=256){
    int d = gidx(dstv, base+t, i64);
    atomicAdd(&bins[d>>8], 1);
  }
  __syncthreads();
  for (int i=tid;i<NB;i+=256){
    int v = bins[i];
    if (v) atomicAdd(&bcnt[i], v);
  }
}

// single-block exclusive scan of NB (<=1024) bucket counts -> bbase, gcur
__global__ __launch_bounds__(1024) void k_bscan(const int* __restrict__ bcnt,
    int* __restrict__ bbase, int* __restrict__ gcur, int NB, int E)
{
  __shared__ int wsum[16];
  int tid=threadIdx.x, lane=tid&63, w=tid>>6;
  int v = (tid<NB)? bcnt[tid]:0;
  int x=v;
  #pragma unroll
  for (int d=1;d<64;d<<=1){ int t=__shfl_up(x,d,64); if(lane>=d) x+=t; }
  if (lane==63) wsum[w]=x;
  __syncthreads();
  if (w==0 && lane<16){
    int y=wsum[lane];
    #pragma unroll
    for (int d=1;d<16;d<<=1){ int t=__shfl_up(y,d,64); if(lane>=d) y+=t; }
    wsum[lane]=y;
  }
  __syncthreads();
  int wb = (w>0)? wsum[w-1]:0;
  int ex = x - v + wb;                 // exclusive prefix
  if (tid<NB){ bbase[tid]=ex; gcur[tid]=ex; }
  if (tid==0) bbase[NB]=E;
}

// PHASE 1: bucket edges by dst>>8 into btmp (unordered within bucket).
// Per block: LDS histogram -> one global atomicAdd per bucket reserves a
// contiguous run -> scatter into runs of ~BCH/NB contiguous records.
__global__ __launch_bounds__(256) void k_bucket(
    const void* __restrict__ srcv, const void* __restrict__ dstv,
    int* __restrict__ gcur, uint2* __restrict__ btmp,
    const int* __restrict__ iflag, int E, int NB)
{
  __shared__ int hist[HNB];
  __shared__ int cbase[HNB];
  int i64 = *iflag;
  int tid = threadIdx.x;
  long base = (long)blockIdx.x * BCH;
  long rem = (long)E - base;
  int nloc = (rem < BCH) ? (int)rem : BCH;
  if (nloc <= 0) return;
  for (int i = tid; i < NB; i += 256) hist[i] = 0;
  __syncthreads();
  int dl[BCH/256];
  #pragma unroll
  for (int k = 0; k < BCH/256; k++){
    int t = tid + k*256;
    dl[k] = -1;
    if (t < nloc){
      int d = gidx(dstv, base + t, i64);
      dl[k] = d;
      atomicAdd(&hist[d>>8], 1);
    }
  }
  __syncthreads();
  for (int i = tid; i < NB; i += 256){
    int hv = hist[i];
    cbase[i] = hv ? atomicAdd(&gcur[i], hv) : 0;
    hist[i] = 0;                      // reuse as local cursor
  }
  __syncthreads();
  #pragma unroll
  for (int k = 0; k < BCH/256; k++){
    int t = tid + k*256;
    if (t < nloc){
      int d = dl[k];
      int s = gidx(srcv, base + t, i64);
      int b = d>>8;
      int slot = cbase[b] + atomicAdd(&hist[b], 1);
      uint2 r; r.x = ((unsigned)d<<16) | (unsigned)s; r.y = (unsigned)(base + t);
      btmp[slot] = r;
    }
  }
}

// PHASE 2: one block per bucket. Counts its 256 nodes' degrees in LDS,
// block-scans them -> writes node-level CSR off[] (coalesced) AND places
// records at final rank via LDS staging -> linear write-out. Overflow
// bucket (>P2CAP, ~45 sigma above mean) falls back to direct scatter.
__global__ __launch_bounds__(256) void k_bsort(
    const int* __restrict__ bbase, const uint2* __restrict__ btmp,
    uint2* __restrict__ sde8, int* __restrict__ off, int N, int NB)
{
  __shared__ int lcnt[NPB];
  __shared__ int lbase[NPB];
  __shared__ int wsum2[4];
  __shared__ uint2 lrec[P2CAP];
  int bkt = blockIdx.x;
  int base = bbase[bkt], endp = bbase[bkt+1];
  int sz = endp - base;
  int lo = bkt*NPB;
  int tid = threadIdx.x;
  lcnt[tid] = 0;
  __syncthreads();
  // pass 1: per-node degree count (btmp slice -> L2-resident for pass 2)
  for (int i=tid;i<sz;i+=256){
    uint2 r = btmp[base+i];
    atomicAdd(&lcnt[(int)(r.x>>16) - lo], 1);
  }
  __syncthreads();
  // block-wide exclusive scan of 256 counts
  int v = lcnt[tid];
  int lane = tid&63, w = tid>>6;
  int x = v;
  #pragma unroll
  for (int d=1;d<64;d<<=1){ int t=__shfl_up(x,d,64); if(lane>=d) x+=t; }
  if (lane==63) wsum2[w]=x;
  __syncthreads();
  if (tid==0){ int a=0; for(int i=0;i<4;i++){ int t=wsum2[i]; wsum2[i]=a; a+=t; } }
  __syncthreads();
  int ex = x - v + wsum2[w];
  lbase[tid] = ex;
  int node = lo + tid;
  if (node < N) off[node] = base + ex;           // node-level CSR offset
  if (bkt == NB-1 && tid == 0) off[N] = bbase[NB];
  __syncthreads();
  if (sz <= P2CAP){
    lcnt[tid] = lbase[tid];                      // reuse as cursor
    __syncthreads();
    for (int i=tid;i<sz;i+=256){
      uint2 r = btmp[base+i];
      int d = (int)(r.x>>16) - lo;
      int p = atomicAdd(&lcnt[d],1);
      lrec[p] = r;
    }
    __syncthreads();
    for (int i=tid;i<sz;i+=256)
      sde8[base+i] = lrec[i];
  } else {
    lcnt[tid] = base + lbase[tid];
    __syncthreads();
    for (int i=tid;i<sz;i+=256){
      uint2 r = btmp[base+i];
      int d = (int)(r.x>>16) - lo;
      int p = atomicAdd(&lcnt[d],1);
      sde8[p] = r;
    }
  }
}

// stream sde8: emit csr_sd sequentially + fill ebuf (fp16) from L1-resident e_emb table
__global__ void k_fill(const uint2* __restrict__ sde8, const void* __restrict__ e_tok,
                       const float* __restrict__ e_emb,
                       unsigned* __restrict__ csr_sd, unsigned short* __restrict__ ebuf,
                       const int* __restrict__ iflag, int E){
  int i64 = *iflag;
  long idx = (long)blockIdx.x*blockDim.x + threadIdx.x;
  if (idx >= (long)E*4) return;
  int pos = (int)(idx>>2), j = (int)(idx&3);
  uint2 r = sde8[pos];
  if (j==0) csr_sd[pos] = r.x;
  int t = gidx(e_tok, (int)r.y, i64);
  const float4* sp = reinterpret_cast<const float4*>(e_emb + t*DD) + j*2;
  float4 x = sp[0], y = sp[1];
  uint4 ov;
  ov.x = (unsigned)f2h(x.x) | ((unsigned)f2h(x.y)<<16);
  ov.y = (unsigned)f2h(x.z) | ((unsigned)f2h(x.w)<<16);
  ov.z = (unsigned)f2h(y.x) | ((unsigned)f2h(y.y)<<16);
  ov.w = (unsigned)f2h(y.z) | ((unsigned)f2h(y.w)<<16);
  reinterpret_cast<uint4*>(ebuf)[(long)pos*4+j] = ov;
}

// hA16=h16@Wni, hB16=h16@Wnj   (first layer only)
__global__ __launch_bounds__(256) void k_nodeAB(
    const unsigned short* __restrict__ h16,
    const float* __restrict__ WA, const float* __restrict__ WB,
    unsigned short* __restrict__ hA16, unsigned short* __restrict__ hB16, int N)
{
  __shared__ float hl[8][DD];
  int tid = threadIdx.x;
  int ln = tid>>5, c = tid&31;
  int n = blockIdx.x*8 + ln;
  hl[ln][c] = (n<N)? h2f(h16[(long)n*DD+c]) : 0.f;
  __syncthreads();
  float a=0.f,b=0.f;
  #pragma unroll
  for (int k=0;k<DD;k++){
    float v = hl[ln][k];
    a = fmaf(v, WA[k*DD+c], a);
    b = fmaf(v, WB[k*DD+c], b);
  }
  if (n<N){ hA16[(long)n*DD+c]=f2h(a); hB16[(long)n*DD+c]=f2h(b); }
}

// MFMA fp16 edge kernel, SOFTWARE-PIPELINED depth 2: one wave = 16 edges.
// D[m][n=edge]=Wf^T·e^T; f=leaky(D+hA[src]+hB[dst]+b); ebuf<-f; lbuf=exp(f·attn)
__global__ __launch_bounds__(256) void k_edge(
    unsigned short* __restrict__ ebuf,
    const unsigned short* __restrict__ hA16, const unsigned short* __restrict__ hB16,
    const unsigned* __restrict__ csr_sd,
    const float* __restrict__ Wf, const float* __restrict__ bvec,
    const float* __restrict__ attn,
    unsigned short* __restrict__ lbuf, int ntiles, int writef)
{
  int lane = threadIdx.x & 63;
  int wid = (blockIdx.x*256 + threadIdx.x) >> 6;
  int nw  = (gridDim.x*256) >> 6;
  int m = lane & 15, q = lane >> 4;
  half8 a0, a1;
  #pragma unroll
  for (int j=0;j<8;j++){
    a0[j] = (_Float16)Wf[(q*8+j)*DD + m];
    a1[j] = (_Float16)Wf[(q*8+j)*DD + 16 + m];
  }
  float4 blo = *reinterpret_cast<const float4*>(bvec + q*4);
  float4 bhi = *reinterpret_cast<const float4*>(bvec + 16 + q*4);
  float4 alo = *reinterpret_cast<const float4*>(attn + q*4);
  float4 ahi = *reinterpret_cast<const float4*>(attn + 16 + q*4);
  f32x4 zero = {0.f,0.f,0.f,0.f};
  // depth-2 preamble: tile0 = fully loaded; tile1 = sd+b loaded
  HU4 b0; b0.u = make_uint4(0,0,0,0);
  HU4 b1; b1.u = make_uint4(0,0,0,0);
  unsigned sd0 = 0, sd1 = 0;
  uint2 gA0_0={0,0}, gA1_0={0,0}, gB0_0={0,0}, gB1_0={0,0};
  if (wid < ntiles){
    long e0 = (long)wid*16 + m;
    sd0 = csr_sd[e0];
    b0.u = *reinterpret_cast<const uint4*>(ebuf + e0*DD + q*8);
    unsigned s = sd0 & 0xFFFFu, d = sd0 >> 16;
    const uint2* pA = reinterpret_cast<const uint2*>(hA16 + (long)s*DD);
    const uint2* pB = reinterpret_cast<const uint2*>(hB16 + (long)d*DD);
    gA0_0=pA[q]; gA1_0=pA[4+q]; gB0_0=pB[q]; gB1_0=pB[4+q];
  }
  if (wid + nw < ntiles){
    long e1 = (long)(wid+nw)*16 + m;
    sd1 = csr_sd[e1];
    b1.u = *reinterpret_cast<const uint4*>(ebuf + e1*DD + q*8);
  }
  for (int t = wid; t < ntiles; t += nw){
    int t1 = t + nw, t2 = t + 2*nw;
    // 1) issue sd/b for tile t+2nw (fully independent)
    unsigned sd2 = 0; HU4 b2; b2.u = make_uint4(0,0,0,0);
    if (t2 < ntiles){
      long e2 = (long)t2*16 + m;
      sd2 = csr_sd[e2];
      b2.u = *reinterpret_cast<const uint4*>(ebuf + e2*DD + q*8);
    }
    // 2) issue gathers for tile t+nw (dep: sd1, resident since last iteration)
    uint2 gA0_1={0,0}, gA1_1={0,0}, gB0_1={0,0}, gB1_1={0,0};
    if (t1 < ntiles){
      unsigned s = sd1 & 0xFFFFu, d = sd1 >> 16;
      const uint2* pA = reinterpret_cast<const uint2*>(hA16 + (long)s*DD);
      const uint2* pB = reinterpret_cast<const uint2*>(hB16 + (long)d*DD);
      gA0_1=pA[q]; gA1_1=pA[4+q]; gB0_1=pB[q]; gB1_1=pB[4+q];
    }
    // 3) MFMA on current tile (b0 resident)
    f32x4 d0 = __builtin_amdgcn_mfma_f32_16x16x32_f16(a0, b0.h, zero, 0,0,0);
    f32x4 d1 = __builtin_amdgcn_mfma_f32_16x16x32_f16(a1, b0.h, zero, 0,0,0);
    // 4) epilogue with current gathers (issued a full iteration ago)
    long tbase = (long)t*16;
    long edge = tbase + m;
    float4 A0 = up4(gA0_0), A1 = up4(gA1_0);
    float4 B0 = up4(gB0_0), B1 = up4(gB1_0);
    float f00 = d0[0]+A0.x+B0.x+blo.x, f01 = d0[1]+A0.y+B0.y+blo.y;
    float f02 = d0[2]+A0.z+B0.z+blo.z, f03 = d0[3]+A0.w+B0.w+blo.w;
    float f10 = d1[0]+A1.x+B1.x+bhi.x, f11 = d1[1]+A1.y+B1.y+bhi.y;
    float f12 = d1[2]+A1.z+B1.z+bhi.z, f13 = d1[3]+A1.w+B1.w+bhi.w;
    f00 = (f00>0.f)?f00:0.01f*f00; f01 = (f01>0.f)?f01:0.01f*f01;
    f02 = (f02>0.f)?f02:0.01f*f02; f03 = (f03>0.f)?f03:0.01f*f03;
    f10 = (f10>0.f)?f10:0.01f*f10; f11 = (f11>0.f)?f11:0.01f*f11;
    f12 = (f12>0.f)?f12:0.01f*f12; f13 = (f13>0.f)?f13:0.01f*f13;
    if (writef){
      uint2 w0, w1;
      w0.x = (unsigned)f2h(f00) | ((unsigned)f2h(f01)<<16);
      w0.y = (unsigned)f2h(f02) | ((unsigned)f2h(f03)<<16);
      w1.x = (unsigned)f2h(f10) | ((unsigned)f2h(f11)<<16);
      w1.y = (unsigned)f2h(f12) | ((unsigned)f2h(f13)<<16);
      *reinterpret_cast<uint2*>(ebuf + edge*DD + q*4) = w0;
      *reinterpret_cast<uint2*>(ebuf + edge*DD + 16 + q*4) = w1;
    }
    float l = f00*alo.x + f01*alo.y + f02*alo.z + f03*alo.w
            + f10*ahi.x + f11*ahi.y + f12*ahi.z + f13*ahi.w;
    l += __shfl_xor(l, 16, 64);
    l += __shfl_xor(l, 32, 64);
    if (lane < 16){
      float lc = fminf(fmaxf(l, -15.f), 10.5f);
      lbuf[tbase + lane] = f2h(__expf(lc));   // max-free softmax weight
    }
    // rotate pipeline
    sd0 = sd1; b0 = b1;
    gA0_0=gA0_1; gA1_0=gA1_1; gB0_0=gB0_1; gB1_0=gB1_1;
    sd1 = sd2; b1 = b2;
  }
}

// per dst node (32 lanes, CSR): g16 = fp16( (sum ex*h16[src]) / (sum ex) )
__global__ __launch_bounds__(256) void k_aggr(
    const unsigned short* __restrict__ h16, const unsigned short* __restrict__ lbuf,
    const int* __restrict__ off, const unsigned* __restrict__ csr_sd,
    unsigned short* __restrict__ g16, int N)
{
  int tid=threadIdx.x;
  int n = blockIdx.x*8 + (tid>>5);
  int c = tid&31;
  if (n>=N) return;
  int o0 = off[n], o1 = off[n+1];
  float num=0.f, den=0.f;
  for (int i=o0;i<o1;i++){
    float ex = h2f(lbuf[i]);
    unsigned s = csr_sd[i] & 0xFFFFu;
    num = fmaf(ex, h2f(h16[(long)s*DD+c]), num);
    den += ex;
  }
  g16[(long)n*DD+c] = f2h((den>0.f) ? num/den : 0.f);
}

// fused proj + next-layer nodeAB: h16 = relu(g@Wnd); hA16 = h@WA; hB16 = h@WB
__global__ __launch_bounds__(256) void k_pnAB(
    const unsigned short* __restrict__ g16, const float* __restrict__ Wnd,
    const float* __restrict__ WA, const float* __restrict__ WB,
    unsigned short* __restrict__ h16,
    unsigned short* __restrict__ hA16, unsigned short* __restrict__ hB16, int N)
{
  __shared__ float gl[8][DD];
  __shared__ float tl[8][DD];
  int tid = threadIdx.x;
  int ln = tid>>5, c = tid&31;
  int n = blockIdx.x*8 + ln;
  gl[ln][c] = (n<N)? h2f(g16[(long)n*DD+c]) : 0.f;
  __syncthreads();
  float t=0.f;
  #pragma unroll
  for (int k=0;k<DD;k++) t = fmaf(gl[ln][k], Wnd[k*DD+c], t);
  t = fmaxf(t, 0.f);
  tl[ln][c] = t;
  __syncthreads();
  float a=0.f,b=0.f;
  #pragma unroll
  for (int k=0;k<DD;k++){
    float v = tl[ln][k];
    a = fmaf(v, WA[k*DD+c], a);
    b = fmaf(v, WB[k*DD+c], b);
  }
  if (n<N){
    h16[(long)n*DD+c]=f2h(t);
    hA16[(long)n*DD+c]=f2h(a);
    hB16[(long)n*DD+c]=f2h(b);
  }
}

// final proj: h(fp32) = relu(g @ Wnode)
__global__ __launch_bounds__(256) void k_proj(
    const unsigned short* __restrict__ g16, const float* __restrict__ W,
    float* __restrict__ h, int N)
{
  __shared__ float gl[8][DD];
  int tid = threadIdx.x;
  int ln = tid>>5, c = tid&31;
  int n = blockIdx.x*8 + ln;
  gl[ln][c] = (n<N)? h2f(g16[(long)n*DD+c]) : 0.f;
  __syncthreads();
  float a=0.f;
  #pragma unroll
  for (int k=0;k<DD;k++) a = fmaf(gl[ln][k], W[k*DD+c], a);
  if (n<N) h[(long)n*DD+c] = fmaxf(a, 0.f);
}

__global__ void k_keys(const float* __restrict__ h, unsigned long long* __restrict__ keys, int N){
  int n = blockIdx.x*blockDim.x + threadIdx.x;
  if (n>=N) return;
  const float4* p = reinterpret_cast<const float4*>(h + (long)n*DD);
  float m = -1e38f;
  #pragma unroll
  for (int j=0;j<8;j++){
    float4 v = p[j];
    m = fmaxf(m, fmaxf(fmaxf(v.x,v.y), fmaxf(v.z,v.w)));
  }
  keys[n] = ((unsigned long long)encf(m)<<32) | (unsigned)(~(unsigned)n);
}

// parallel top-8: per-thread register top-8 + 8-round block tournament (keys unique)
__global__ __launch_bounds__(256) void k_ptop(const unsigned long long* __restrict__ keys, int N,
                                              unsigned long long* __restrict__ outk){
  __shared__ unsigned long long red[256];
  int tid = threadIdx.x, b = blockIdx.x, nb = gridDim.x;
  int chunk = (N + nb - 1) / nb;
  int base = b*chunk, end = base+chunk; if (end>N) end=N;
  unsigned long long loc[TOPK];
  #pragma unroll
  for (int i=0;i<TOPK;i++) loc[i]=0ull;
  for (int i=base+tid; i<end; i+=256){
    unsigned long long k = keys[i];
    if (k > loc[TOPK-1]){
      int j = TOPK-1;
      while (j>0 && loc[j-1]<k){ loc[j]=loc[j-1]; j--; }
      loc[j]=k;
    }
  }
  for (int r=0; r<TOPK; r++){
    red[tid] = loc[0];
    __syncthreads();
    for (int s=128; s>0; s>>=1){
      if (tid<s && red[tid+s]>red[tid]) red[tid]=red[tid+s];
      __syncthreads();
    }
    unsigned long long w = red[0];
    if (tid==0) outk[b*TOPK + r] = w;
    if (loc[0]==w){
      #pragma unroll
      for (int j=0;j<TOPK-1;j++) loc[j]=loc[j+1];
      loc[TOPK-1]=0ull;
    }
    __syncthreads();
  }
}

__global__ __launch_bounds__(256) void k_head(
    const float* __restrict__ h, const unsigned long long* __restrict__ sel,
    const float* __restrict__ Wlin, const float* __restrict__ blin,
    const float* __restrict__ W1, const float* __restrict__ b1,
    const float* __restrict__ W2, const float* __restrict__ b2,
    const float* __restrict__ Wc, const float* __restrict__ bc,
    float* __restrict__ out, int N)
{
  __shared__ float xs[TOPK][DD];
  __shared__ float y1[DD], y2[DD], y3[DD];
  int tid=threadIdx.x;
  int r=tid>>5, c=tid&31;
  unsigned node = ~(unsigned)(sel[r] & 0xFFFFFFFFull);
  if (node >= (unsigned)N) node = 0;
  xs[r][c] = h[(long)node*DD + c];
  __syncthreads();
  if (tid<TOPK){
    for (int i=1;i<DD;i++){
      float v=xs[tid][i]; int j=i-1;
      while (j>=0 && xs[tid][j]>v){ xs[tid][j+1]=xs[tid][j]; j--; }
      xs[tid][j+1]=v;
    }
  }
  __syncthreads();
  if (tid<DD){
    float a=blin[tid];
    for (int i=0;i<TOPK*DD;i++) a = fmaf(xs[i>>5][i&31], Wlin[i*DD+tid], a);
    y1[tid] = a>0.f? a : 0.f;
  }
  __syncthreads();
  if (tid<DD){
    float a=b1[tid];
    #pragma unroll
    for (int i=0;i<DD;i++) a = fmaf(y1[i], W1[i*DD+tid], a);
    y2[tid] = a>0.f? a : 0.f;
  }
  __syncthreads();
  if (tid<DD){
    float a=b2[tid];
    #pragma unroll
    for (int i=0;i<DD;i++) a = fmaf(y2[i], W2[i*DD+tid], a);
    y3[tid] = a>0.f? a : 0.f;
  }
  __syncthreads();
  if (tid<2){
    float a=bc[tid];
    #pragma unroll
    for (int i=0;i<DD;i++) a = fmaf(y3[i], Wc[i*2+tid], a);
    out[tid] = a;                       // fp32 output
  }
}

extern "C" void kernel_launch(void* const* d_in, const int* in_sizes, int n_in,
                              void* d_out, int out_size, void* d_ws, size_t ws_size,
                              hipStream_t stream) {
  const int N = in_sizes[0];
  const int E = in_sizes[1];
  const float* tok_emb   = (const float*)d_in[4];
  const float* e_tok_emb = (const float*)d_in[5];
  const float* W_ni  = (const float*)d_in[6];
  const float* W_nj  = (const float*)d_in[7];
  const float* W_fij = (const float*)d_in[8];
  const float* b_e   = (const float*)d_in[9];
  const float* attn  = (const float*)d_in[10];
  const float* W_nd  = (const float*)d_in[11];

  char* p = (char*)d_ws;
  auto alloc = [&](size_t bytes)->char* {
    char* r = p; p += (bytes + 255) & ~(size_t)255; return r;
  };
  // ~131.5 MB total (sde8 aliases h+g16+lbuf; btmp aliases ebuf; all dead at setup)
  int* iflag = (int*)alloc(256);
  unsigned long long* sel = (unsigned long long*)alloc(256);
  unsigned long long* cand = (unsigned long long*)alloc(256*TOPK*8);
  int* bcnt = (int*)alloc(HNB*4);
  int* bbase = (int*)alloc((HNB+1)*4);
  int* gcur = (int*)alloc(HNB*4);
  int* csroff = (int*)alloc((size_t)(N+1)*4);
  unsigned* csr_sd = (unsigned*)alloc((size_t)(E+32)*4);
  float* h = (float*)alloc((size_t)N*DD*4);                     // fp32, final only
  unsigned short* g16  = (unsigned short*)alloc((size_t)N*DD*2);
  unsigned short* lbuf = (unsigned short*)alloc((size_t)(E+32)*2);
  unsigned short* h16  = (unsigned short*)alloc((size_t)N*DD*2);
  unsigned short* hA16 = (unsigned short*)alloc((size_t)N*DD*2);
  unsigned short* hB16 = (unsigned short*)alloc((size_t)N*DD*2);
  unsigned short* ebuf = (unsigned short*)alloc((size_t)(E+32)*DD*2);
  uint2* sde8 = (uint2*)h;                        // alias: spans h+g16+lbuf (12.8 MB)
  uint2* btmp = (uint2*)ebuf;                     // alias: ebuf dead until k_fill
  unsigned long long* keys = (unsigned long long*)lbuf;  // alias: lbuf dead after last aggr

  const int NB = (N + NPB - 1) / NPB;             // buckets (196 @ N=50k)
  const int NECH = (E + BCH - 1) / BCH;

  hipLaunchKernelGGL(k_detect, dim3(1), dim3(1024), 0, stream, (const int*)d_in[2], iflag, bcnt);
  hipLaunchKernelGGL(k_init, dim3((int)(((long)N*8+255)/256)), dim3(256), 0, stream,
                     d_in[0], tok_emb, h16, iflag, N);
  hipLaunchKernelGGL(k_hist, dim3(NECH), dim3(256), 0, stream,
                     d_in[3], bcnt, iflag, E, NB);
  hipLaunchKernelGGL(k_bscan, dim3(1), dim3(1024), 0, stream, bcnt, bbase, gcur, NB, E);
  hipLaunchKernelGGL(k_bucket, dim3(NECH), dim3(256), 0, stream,
                     d_in[2], d_in[3], gcur, btmp, iflag, E, NB);
  hipLaunchKernelGGL(k_bsort, dim3(NB), dim3(256), 0, stream, bbase, btmp, sde8, csroff, N, NB);
  hipLaunchKernelGGL(k_fill, dim3((int)(((long)E*4+255)/256)), dim3(256), 0, stream,
                     sde8, d_in[1], e_tok_emb, csr_sd, ebuf, iflag, E);

  int nb_node = (N+7)/8;
  int ntiles = (E+15)/16;
  hipLaunchKernelGGL(k_nodeAB, dim3(nb_node), dim3(256), 0, stream,
                     h16, W_ni, W_nj, hA16, hB16, N);
  for (int l=0; l<NLAYERS; l++){
    const float* Wf  = W_fij + (size_t)l*DD*DD;
    const float* bl  = b_e   + (size_t)l*DD;
    const float* at  = attn  + (size_t)l*DD;
    const float* Wnd = W_nd  + (size_t)l*DD*DD;
    hipLaunchKernelGGL(k_edge, dim3(2048), dim3(256), 0, stream,
                       ebuf, hA16, hB16, csr_sd, Wf, bl, at, lbuf, ntiles,
                       (l < NLAYERS-1) ? 1 : 0);
    hipLaunchKernelGGL(k_aggr, dim3(nb_node), dim3(256), 0, stream,
                       h16, lbuf, csroff, csr_sd, g16, N);
    if (l < NLAYERS-1){
      const float* WnA = W_ni + (size_t)(l+1)*DD*DD;
      const float* WnB = W_nj + (size_t)(l+1)*DD*DD;
      hipLaunchKernelGGL(k_pnAB, dim3(nb_node), dim3(256), 0, stream,
                         g16, Wnd, WnA, WnB, h16, hA16, hB16, N);
    } else {
      hipLaunchKernelGGL(k_proj, dim3(nb_node), dim3(256), 0, stream,
                         g16, Wnd, h, N);
    }
  }

  hipLaunchKernelGGL(k_keys, dim3((N+255)/256), dim3(256), 0, stream, h, keys, N);
  hipLaunchKernelGGL(k_ptop, dim3(256), dim3(256), 0, stream, keys, N, cand);
  hipLaunchKernelGGL(k_ptop, dim3(1), dim3(256), 0, stream, cand, 256*TOPK, sel);
  hipLaunchKernelGGL(k_head, dim3(1), dim3(256), 0, stream,
                     h, sel,
                     (const float*)d_in[12], (const float*)d_in[13],
                     (const float*)d_in[14], (const float*)d_in[15],
                     (const float*)d_in[16], (const float*)d_in[17],
                     (const float*)d_in[18], (const float*)d_in[19],
                     (float*)d_out, N);
}

// Round 4
// 1030.960 us; speedup vs baseline: 1.3776x; 1.2354x over previous
//
#include <hip/hip_runtime.h>
#include <hip/hip_fp16.h>

#define DD 32
#define NLAYERS 8
#define TOPK 8
#define NPB 256      // nodes per bucket (power of 2 -> bucket = dst>>8)
#define HNB 1024     // max buckets supported (N <= 262144)
#define BCH 4096     // edges per phase-1 block
#define P2CAP 12288  // phase-2 LDS record capacity (96 KB; bucket mean ~8192, sigma ~90)

typedef _Float16 half8 __attribute__((ext_vector_type(8)));
typedef float f32x4 __attribute__((ext_vector_type(4)));

__device__ __forceinline__ unsigned encf(float x){ unsigned u=__float_as_uint(x); return (u&0x80000000u)? ~u : (u|0x80000000u); }
__device__ __forceinline__ unsigned short f2h(float f){ return __half_as_ushort(__float2half(f)); }
__device__ __forceinline__ float h2f(unsigned short u){ return __half2float(__ushort_as_half(u)); }
__device__ __forceinline__ float4 up4(uint2 u){
  float4 r;
  r.x=h2f((unsigned short)(u.x&0xFFFFu)); r.y=h2f((unsigned short)(u.x>>16));
  r.z=h2f((unsigned short)(u.y&0xFFFFu)); r.w=h2f((unsigned short)(u.y>>16));
  return r;
}
union HU { uint2 u; half8 h; };   // b-fragment reinterpret (8 fp16 = 4 VGPRs... 2x uint2)
union HU4 { uint4 u; half8 h; };
__device__ __forceinline__ int gidx(const void* p, long i, int i64){
  return i64 ? (int)((const long long*)p)[i] : ((const int*)p)[i];
}

// also zeroes bcnt (bucket histogram) to avoid an extra launch
__global__ __launch_bounds__(1024) void k_detect(const int* __restrict__ srcw,
                                                 int* __restrict__ iflag,
                                                 int* __restrict__ bcnt){
  int tid = threadIdx.x;
  for (int i=tid;i<HNB;i+=1024) bcnt[i]=0;
  if (tid==0){
    int allz = 1;
    for (int k=1;k<32;k+=2) if (srcw[k]!=0) allz = 0;
    *iflag = allz;
  }
}

// h16 = fp16(relu(tok_emb[h_tok]))
__global__ void k_init(const void* __restrict__ h_tok,
                       const float* __restrict__ tok_emb,
                       unsigned short* __restrict__ h16,
                       const int* __restrict__ iflag, int N)
{
  int i64 = *iflag;
  long idx = (long)blockIdx.x*blockDim.x + threadIdx.x;
  if (idx >= (long)N*8) return;
  int n=(int)(idx>>3), q=(int)(idx&7);
  int t = gidx(h_tok, n, i64);
  float4 v = reinterpret_cast<const float4*>(tok_emb)[t*8+q];
  uint2 o;
  o.x = (unsigned)f2h(fmaxf(v.x,0.f)) | ((unsigned)f2h(fmaxf(v.y,0.f))<<16);
  o.y = (unsigned)f2h(fmaxf(v.z,0.f)) | ((unsigned)f2h(fmaxf(v.w,0.f))<<16);
  reinterpret_cast<uint2*>(h16)[(long)n*8+q] = o;
}

// bucket-level histogram: LDS bins + 1 global atomic per (block,bin)
__global__ __launch_bounds__(256) void k_hist(
    const void* __restrict__ dstv, int* __restrict__ bcnt,
    const int* __restrict__ iflag, int E, int NB)
{
  __shared__ int bins[HNB];
  int i64 = *iflag;
  int tid = threadIdx.x;
  for (int i=tid;i<NB;i+=256) bins[i]=0;
  __syncthreads();
  long base = (long)blockIdx.x * BCH;
  long rem = (long)E - base;
  int nloc = (rem < BCH) ? (int)rem : BCH;
  for (int t=tid; t<nloc; t+=256){
    int d = gidx(dstv, base+t, i64);
    atomicAdd(&bins[d>>8], 1);
  }
  __syncthreads();
  for (int i=tid;i<NB;i+=256){
    int v = bins[i];
    if (v) atomicAdd(&bcnt[i], v);
  }
}

// single-block exclusive scan of NB (<=1024) bucket counts -> bbase, gcur
__global__ __launch_bounds__(1024) void k_bscan(const int* __restrict__ bcnt,
    int* __restrict__ bbase, int* __restrict__ gcur, int NB, int E)
{
  __shared__ int wsum[16];
  int tid=threadIdx.x, lane=tid&63, w=tid>>6;
  int v = (tid<NB)? bcnt[tid]:0;
  int x=v;
  #pragma unroll
  for (int d=1;d<64;d<<=1){ int t=__shfl_up(x,d,64); if(lane>=d) x+=t; }
  if (lane==63) wsum[w]=x;
  __syncthreads();
  if (w==0 && lane<16){
    int y=wsum[lane];
    #pragma unroll
    for (int d=1;d<16;d<<=1){ int t=__shfl_up(y,d,64); if(lane>=d) y+=t; }
    wsum[lane]=y;
  }
  __syncthreads();
  int wb = (w>0)? wsum[w-1]:0;
  int ex = x - v + wb;                 // exclusive prefix
  if (tid<NB){ bbase[tid]=ex; gcur[tid]=ex; }
  if (tid==0) bbase[NB]=E;
}

// PHASE 1: bucket edges by dst>>8 into btmp (unordered within bucket).
__global__ __launch_bounds__(256) void k_bucket(
    const void* __restrict__ srcv, const void* __restrict__ dstv,
    int* __restrict__ gcur, uint2* __restrict__ btmp,
    const int* __restrict__ iflag, int E, int NB)
{
  __shared__ int hist[HNB];
  __shared__ int cbase[HNB];
  int i64 = *iflag;
  int tid = threadIdx.x;
  long base = (long)blockIdx.x * BCH;
  long rem = (long)E - base;
  int nloc = (rem < BCH) ? (int)rem : BCH;
  if (nloc <= 0) return;
  for (int i = tid; i < NB; i += 256) hist[i] = 0;
  __syncthreads();
  int dl[BCH/256];
  #pragma unroll
  for (int k = 0; k < BCH/256; k++){
    int t = tid + k*256;
    dl[k] = -1;
    if (t < nloc){
      int d = gidx(dstv, base + t, i64);
      dl[k] = d;
      atomicAdd(&hist[d>>8], 1);
    }
  }
  __syncthreads();
  for (int i = tid; i < NB; i += 256){
    int hv = hist[i];
    cbase[i] = hv ? atomicAdd(&gcur[i], hv) : 0;
    hist[i] = 0;                      // reuse as local cursor
  }
  __syncthreads();
  #pragma unroll
  for (int k = 0; k < BCH/256; k++){
    int t = tid + k*256;
    if (t < nloc){
      int d = dl[k];
      int s = gidx(srcv, base + t, i64);
      int b = d>>8;
      int slot = cbase[b] + atomicAdd(&hist[b], 1);
      uint2 r; r.x = ((unsigned)d<<16) | (unsigned)s; r.y = (unsigned)(base + t);
      btmp[slot] = r;
    }
  }
}

// PHASE 2: one block per bucket; derives node CSR offsets + final placement.
__global__ __launch_bounds__(256) void k_bsort(
    const int* __restrict__ bbase, const uint2* __restrict__ btmp,
    uint2* __restrict__ sde8, int* __restrict__ off, int N, int NB)
{
  __shared__ int lcnt[NPB];
  __shared__ int lbase[NPB];
  __shared__ int wsum2[4];
  __shared__ uint2 lrec[P2CAP];
  int bkt = blockIdx.x;
  int base = bbase[bkt], endp = bbase[bkt+1];
  int sz = endp - base;
  int lo = bkt*NPB;
  int tid = threadIdx.x;
  lcnt[tid] = 0;
  __syncthreads();
  for (int i=tid;i<sz;i+=256){
    uint2 r = btmp[base+i];
    atomicAdd(&lcnt[(int)(r.x>>16) - lo], 1);
  }
  __syncthreads();
  int v = lcnt[tid];
  int lane = tid&63, w = tid>>6;
  int x = v;
  #pragma unroll
  for (int d=1;d<64;d<<=1){ int t=__shfl_up(x,d,64); if(lane>=d) x+=t; }
  if (lane==63) wsum2[w]=x;
  __syncthreads();
  if (tid==0){ int a=0; for(int i=0;i<4;i++){ int t=wsum2[i]; wsum2[i]=a; a+=t; } }
  __syncthreads();
  int ex = x - v + wsum2[w];
  lbase[tid] = ex;
  int node = lo + tid;
  if (node < N) off[node] = base + ex;           // node-level CSR offset
  if (bkt == NB-1 && tid == 0) off[N] = bbase[NB];
  __syncthreads();
  if (sz <= P2CAP){
    lcnt[tid] = lbase[tid];                      // reuse as cursor
    __syncthreads();
    for (int i=tid;i<sz;i+=256){
      uint2 r = btmp[base+i];
      int d = (int)(r.x>>16) - lo;
      int p = atomicAdd(&lcnt[d],1);
      lrec[p] = r;
    }
    __syncthreads();
    for (int i=tid;i<sz;i+=256)
      sde8[base+i] = lrec[i];
  } else {
    lcnt[tid] = base + lbase[tid];
    __syncthreads();
    for (int i=tid;i<sz;i+=256){
      uint2 r = btmp[base+i];
      int d = (int)(r.x>>16) - lo;
      int p = atomicAdd(&lcnt[d],1);
      sde8[p] = r;
    }
  }
}

// stream sde8: emit csr_sd sequentially + fill ebuf (fp16) from L1-resident e_emb table
__global__ void k_fill(const uint2* __restrict__ sde8, const void* __restrict__ e_tok,
                       const float* __restrict__ e_emb,
                       unsigned* __restrict__ csr_sd, unsigned short* __restrict__ ebuf,
                       const int* __restrict__ iflag, int E){
  int i64 = *iflag;
  long idx = (long)blockIdx.x*blockDim.x + threadIdx.x;
  if (idx >= (long)E*4) return;
  int pos = (int)(idx>>2), j = (int)(idx&3);
  uint2 r = sde8[pos];
  if (j==0) csr_sd[pos] = r.x;
  int t = gidx(e_tok, (int)r.y, i64);
  const float4* sp = reinterpret_cast<const float4*>(e_emb + t*DD) + j*2;
  float4 x = sp[0], y = sp[1];
  uint4 ov;
  ov.x = (unsigned)f2h(x.x) | ((unsigned)f2h(x.y)<<16);
  ov.y = (unsigned)f2h(x.z) | ((unsigned)f2h(x.w)<<16);
  ov.z = (unsigned)f2h(y.x) | ((unsigned)f2h(y.y)<<16);
  ov.w = (unsigned)f2h(y.z) | ((unsigned)f2h(y.w)<<16);
  reinterpret_cast<uint4*>(ebuf)[(long)pos*4+j] = ov;
}

// hA16=h16@Wni, hB16=h16@Wnj   (first layer only)
__global__ __launch_bounds__(256) void k_nodeAB(
    const unsigned short* __restrict__ h16,
    const float* __restrict__ WA, const float* __restrict__ WB,
    unsigned short* __restrict__ hA16, unsigned short* __restrict__ hB16, int N)
{
  __shared__ float hl[8][DD];
  int tid = threadIdx.x;
  int ln = tid>>5, c = tid&31;
  int n = blockIdx.x*8 + ln;
  hl[ln][c] = (n<N)? h2f(h16[(long)n*DD+c]) : 0.f;
  __syncthreads();
  float a=0.f,b=0.f;
  #pragma unroll
  for (int k=0;k<DD;k++){
    float v = hl[ln][k];
    a = fmaf(v, WA[k*DD+c], a);
    b = fmaf(v, WB[k*DD+c], b);
  }
  if (n<N){ hA16[(long)n*DD+c]=f2h(a); hB16[(long)n*DD+c]=f2h(b); }
}

// MFMA fp16 edge kernel, SOFTWARE-PIPELINED depth 2: one wave = 16 edges.
// D[m][n=edge]=Wf^T·e^T; f=leaky(D+hA[src]+hB[dst]+b); ebuf<-f; lbuf=exp(f·attn)
__global__ __launch_bounds__(256) void k_edge(
    unsigned short* __restrict__ ebuf,
    const unsigned short* __restrict__ hA16, const unsigned short* __restrict__ hB16,
    const unsigned* __restrict__ csr_sd,
    const float* __restrict__ Wf, const float* __restrict__ bvec,
    const float* __restrict__ attn,
    unsigned short* __restrict__ lbuf, int ntiles, int writef)
{
  int lane = threadIdx.x & 63;
  int wid = (blockIdx.x*256 + threadIdx.x) >> 6;
  int nw  = (gridDim.x*256) >> 6;
  int m = lane & 15, q = lane >> 4;
  half8 a0, a1;
  #pragma unroll
  for (int j=0;j<8;j++){
    a0[j] = (_Float16)Wf[(q*8+j)*DD + m];
    a1[j] = (_Float16)Wf[(q*8+j)*DD + 16 + m];
  }
  float4 blo = *reinterpret_cast<const float4*>(bvec + q*4);
  float4 bhi = *reinterpret_cast<const float4*>(bvec + 16 + q*4);
  float4 alo = *reinterpret_cast<const float4*>(attn + q*4);
  float4 ahi = *reinterpret_cast<const float4*>(attn + 16 + q*4);
  f32x4 zero = {0.f,0.f,0.f,0.f};
  // depth-2 preamble: tile0 = fully loaded; tile1 = sd+b loaded
  HU4 b0; b0.u = make_uint4(0,0,0,0);
  HU4 b1; b1.u = make_uint4(0,0,0,0);
  unsigned sd0 = 0, sd1 = 0;
  uint2 gA0_0={0,0}, gA1_0={0,0}, gB0_0={0,0}, gB1_0={0,0};
  if (wid < ntiles){
    long e0 = (long)wid*16 + m;
    sd0 = csr_sd[e0];
    b0.u = *reinterpret_cast<const uint4*>(ebuf + e0*DD + q*8);
    unsigned s = sd0 & 0xFFFFu, d = sd0 >> 16;
    const uint2* pA = reinterpret_cast<const uint2*>(hA16 + (long)s*DD);
    const uint2* pB = reinterpret_cast<const uint2*>(hB16 + (long)d*DD);
    gA0_0=pA[q]; gA1_0=pA[4+q]; gB0_0=pB[q]; gB1_0=pB[4+q];
  }
  if (wid + nw < ntiles){
    long e1 = (long)(wid+nw)*16 + m;
    sd1 = csr_sd[e1];
    b1.u = *reinterpret_cast<const uint4*>(ebuf + e1*DD + q*8);
  }
  for (int t = wid; t < ntiles; t += nw){
    int t1 = t + nw, t2 = t + 2*nw;
    // 1) issue sd/b for tile t+2nw (fully independent)
    unsigned sd2 = 0; HU4 b2; b2.u = make_uint4(0,0,0,0);
    if (t2 < ntiles){
      long e2 = (long)t2*16 + m;
      sd2 = csr_sd[e2];
      b2.u = *reinterpret_cast<const uint4*>(ebuf + e2*DD + q*8);
    }
    // 2) issue gathers for tile t+nw (dep: sd1, resident since last iteration)
    uint2 gA0_1={0,0}, gA1_1={0,0}, gB0_1={0,0}, gB1_1={0,0};
    if (t1 < ntiles){
      unsigned s = sd1 & 0xFFFFu, d = sd1 >> 16;
      const uint2* pA = reinterpret_cast<const uint2*>(hA16 + (long)s*DD);
      const uint2* pB = reinterpret_cast<const uint2*>(hB16 + (long)d*DD);
      gA0_1=pA[q]; gA1_1=pA[4+q]; gB0_1=pB[q]; gB1_1=pB[4+q];
    }
    // 3) MFMA on current tile (b0 resident)
    f32x4 d0 = __builtin_amdgcn_mfma_f32_16x16x32_f16(a0, b0.h, zero, 0,0,0);
    f32x4 d1 = __builtin_amdgcn_mfma_f32_16x16x32_f16(a1, b0.h, zero, 0,0,0);
    // 4) epilogue with current gathers (issued a full iteration ago)
    long tbase = (long)t*16;
    long edge = tbase + m;
    float4 A0 = up4(gA0_0), A1 = up4(gA1_0);
    float4 B0 = up4(gB0_0), B1 = up4(gB1_0);
    float f00 = d0[0]+A0.x+B0.x+blo.x, f01 = d0[1]+A0.y+B0.y+blo.y;
    float f02 = d0[2]+A0.z+B0.z+blo.z, f03 = d0[3]+A0.w+B0.w+blo.w;
    float f10 = d1[0]+A1.x+B1.x+bhi.x, f11 = d1[1]+A1.y+B1.y+bhi.y;
    float f12 = d1[2]+A1.z+B1.z+bhi.z, f13 = d1[3]+A1.w+B1.w+bhi.w;
    f00 = (f00>0.f)?f00:0.01f*f00; f01 = (f01>0.f)?f01:0.01f*f01;
    f02 = (f02>0.f)?f02:0.01f*f02; f03 = (f03>0.f)?f03:0.01f*f03;
    f10 = (f10>0.f)?f10:0.01f*f10; f11 = (f11>0.f)?f11:0.01f*f11;
    f12 = (f12>0.f)?f12:0.01f*f12; f13 = (f13>0.f)?f13:0.01f*f13;
    if (writef){
      uint2 w0, w1;
      w0.x = (unsigned)f2h(f00) | ((unsigned)f2h(f01)<<16);
      w0.y = (unsigned)f2h(f02) | ((unsigned)f2h(f03)<<16);
      w1.x = (unsigned)f2h(f10) | ((unsigned)f2h(f11)<<16);
      w1.y = (unsigned)f2h(f12) | ((unsigned)f2h(f13)<<16);
      *reinterpret_cast<uint2*>(ebuf + edge*DD + q*4) = w0;
      *reinterpret_cast<uint2*>(ebuf + edge*DD + 16 + q*4) = w1;
    }
    float l = f00*alo.x + f01*alo.y + f02*alo.z + f03*alo.w
            + f10*ahi.x + f11*ahi.y + f12*ahi.z + f13*ahi.w;
    l += __shfl_xor(l, 16, 64);
    l += __shfl_xor(l, 32, 64);
    if (lane < 16){
      float lc = fminf(fmaxf(l, -15.f), 10.5f);
      lbuf[tbase + lane] = f2h(__expf(lc));   // max-free softmax weight
    }
    // rotate pipeline
    sd0 = sd1; b0 = b1;
    gA0_0=gA0_1; gA1_0=gA1_1; gB0_0=gB0_1; gB1_0=gB1_1;
    sd1 = sd2; b1 = b2;
  }
}

// FUSED aggregate + projections. Stage 1: per dst node (32 lanes, CSR),
// unroll-8 independent gathers (was serial dependent-chain: 59us latency-bound,
// 4.9% HBM, 24% VALU). Stage 2 (LDS handoff, same 8-node/block mapping the old
// k_pnAB used): t=relu(g@Wnd); h16out<-t; hA16<-t@WA; hB16<-t@WB  (or fp32 h
// on last layer). h16 is ping-ponged across layers: stage 2 writes h16out
// while other blocks still gather from h16in.
__global__ __launch_bounds__(256) void k_aggrP(
    const unsigned short* __restrict__ h16in, const unsigned short* __restrict__ lbuf,
    const int* __restrict__ off, const unsigned* __restrict__ csr_sd,
    const float* __restrict__ Wnd, const float* __restrict__ WA,
    const float* __restrict__ WB,
    unsigned short* __restrict__ h16out, unsigned short* __restrict__ hA16,
    unsigned short* __restrict__ hB16, float* __restrict__ hout, int N, int last)
{
  __shared__ float gl[8][DD];
  __shared__ float tl[8][DD];
  int tid=threadIdx.x;
  int ln = tid>>5, c = tid&31;
  int n = blockIdx.x*8 + ln;
  float num=0.f, den=0.f;
  if (n<N){
    int o0 = off[n], o1 = off[n+1];
    int i = o0;
    for (; i+8 <= o1; i += 8){
      unsigned sd0=csr_sd[i],   sd1=csr_sd[i+1], sd2=csr_sd[i+2], sd3=csr_sd[i+3];
      unsigned sd4=csr_sd[i+4], sd5=csr_sd[i+5], sd6=csr_sd[i+6], sd7=csr_sd[i+7];
      float ex0=h2f(lbuf[i]),   ex1=h2f(lbuf[i+1]), ex2=h2f(lbuf[i+2]), ex3=h2f(lbuf[i+3]);
      float ex4=h2f(lbuf[i+4]), ex5=h2f(lbuf[i+5]), ex6=h2f(lbuf[i+6]), ex7=h2f(lbuf[i+7]);
      float g0=h2f(h16in[(long)(sd0&0xFFFFu)*DD+c]);
      float g1=h2f(h16in[(long)(sd1&0xFFFFu)*DD+c]);
      float g2=h2f(h16in[(long)(sd2&0xFFFFu)*DD+c]);
      float g3=h2f(h16in[(long)(sd3&0xFFFFu)*DD+c]);
      float g4=h2f(h16in[(long)(sd4&0xFFFFu)*DD+c]);
      float g5=h2f(h16in[(long)(sd5&0xFFFFu)*DD+c]);
      float g6=h2f(h16in[(long)(sd6&0xFFFFu)*DD+c]);
      float g7=h2f(h16in[(long)(sd7&0xFFFFu)*DD+c]);
      num=fmaf(ex0,g0,num); num=fmaf(ex1,g1,num);
      num=fmaf(ex2,g2,num); num=fmaf(ex3,g3,num);
      num=fmaf(ex4,g4,num); num=fmaf(ex5,g5,num);
      num=fmaf(ex6,g6,num); num=fmaf(ex7,g7,num);
      den+=ex0; den+=ex1; den+=ex2; den+=ex3;
      den+=ex4; den+=ex5; den+=ex6; den+=ex7;
    }
    for (; i<o1; i++){
      unsigned sd=csr_sd[i];
      float ex=h2f(lbuf[i]);
      num=fmaf(ex, h2f(h16in[(long)(sd&0xFFFFu)*DD+c]), num);
      den += ex;
    }
  }
  gl[ln][c] = (den>0.f)? num/den : 0.f;
  __syncthreads();
  float t=0.f;
  #pragma unroll
  for (int k=0;k<DD;k++) t = fmaf(gl[ln][k], Wnd[k*DD+c], t);
  t = fmaxf(t, 0.f);
  if (last){
    if (n<N) hout[(long)n*DD+c] = t;
    return;
  }
  tl[ln][c] = t;
  __syncthreads();
  float a=0.f,b=0.f;
  #pragma unroll
  for (int k=0;k<DD;k++){
    float v = tl[ln][k];
    a = fmaf(v, WA[k*DD+c], a);
    b = fmaf(v, WB[k*DD+c], b);
  }
  if (n<N){
    h16out[(long)n*DD+c]=f2h(t);
    hA16[(long)n*DD+c]=f2h(a);
    hB16[(long)n*DD+c]=f2h(b);
  }
}

__global__ void k_keys(const float* __restrict__ h, unsigned long long* __restrict__ keys, int N){
  int n = blockIdx.x*blockDim.x + threadIdx.x;
  if (n>=N) return;
  const float4* p = reinterpret_cast<const float4*>(h + (long)n*DD);
  float m = -1e38f;
  #pragma unroll
  for (int j=0;j<8;j++){
    float4 v = p[j];
    m = fmaxf(m, fmaxf(fmaxf(v.x,v.y), fmaxf(v.z,v.w)));
  }
  keys[n] = ((unsigned long long)encf(m)<<32) | (unsigned)(~(unsigned)n);
}

// parallel top-8: per-thread register top-8 + 8-round block tournament (keys unique)
__global__ __launch_bounds__(256) void k_ptop(const unsigned long long* __restrict__ keys, int N,
                                              unsigned long long* __restrict__ outk){
  __shared__ unsigned long long red[256];
  int tid = threadIdx.x, b = blockIdx.x, nb = gridDim.x;
  int chunk = (N + nb - 1) / nb;
  int base = b*chunk, end = base+chunk; if (end>N) end=N;
  unsigned long long loc[TOPK];
  #pragma unroll
  for (int i=0;i<TOPK;i++) loc[i]=0ull;
  for (int i=base+tid; i<end; i+=256){
    unsigned long long k = keys[i];
    if (k > loc[TOPK-1]){
      int j = TOPK-1;
      while (j>0 && loc[j-1]<k){ loc[j]=loc[j-1]; j--; }
      loc[j]=k;
    }
  }
  for (int r=0; r<TOPK; r++){
    red[tid] = loc[0];
    __syncthreads();
    for (int s=128; s>0; s>>=1){
      if (tid<s && red[tid+s]>red[tid]) red[tid]=red[tid+s];
      __syncthreads();
    }
    unsigned long long w = red[0];
    if (tid==0) outk[b*TOPK + r] = w;
    if (loc[0]==w){
      #pragma unroll
      for (int j=0;j<TOPK-1;j++) loc[j]=loc[j+1];
      loc[TOPK-1]=0ull;
    }
    __syncthreads();
  }
}

__global__ __launch_bounds__(256) void k_head(
    const float* __restrict__ h, const unsigned long long* __restrict__ sel,
    const float* __restrict__ Wlin, const float* __restrict__ blin,
    const float* __restrict__ W1, const float* __restrict__ b1,
    const float* __restrict__ W2, const float* __restrict__ b2,
    const float* __restrict__ Wc, const float* __restrict__ bc,
    float* __restrict__ out, int N)
{
  __shared__ float xs[TOPK][DD];
  __shared__ float y1[DD], y2[DD], y3[DD];
  int tid=threadIdx.x;
  int r=tid>>5, c=tid&31;
  unsigned node = ~(unsigned)(sel[r] & 0xFFFFFFFFull);
  if (node >= (unsigned)N) node = 0;
  xs[r][c] = h[(long)node*DD + c];
  __syncthreads();
  if (tid<TOPK){
    for (int i=1;i<DD;i++){
      float v=xs[tid][i]; int j=i-1;
      while (j>=0 && xs[tid][j]>v){ xs[tid][j+1]=xs[tid][j]; j--; }
      xs[tid][j+1]=v;
    }
  }
  __syncthreads();
  if (tid<DD){
    float a=blin[tid];
    for (int i=0;i<TOPK*DD;i++) a = fmaf(xs[i>>5][i&31], Wlin[i*DD+tid], a);
    y1[tid] = a>0.f? a : 0.f;
  }
  __syncthreads();
  if (tid<DD){
    float a=b1[tid];
    #pragma unroll
    for (int i=0;i<DD;i++) a = fmaf(y1[i], W1[i*DD+tid], a);
    y2[tid] = a>0.f? a : 0.f;
  }
  __syncthreads();
  if (tid<DD){
    float a=b2[tid];
    #pragma unroll
    for (int i=0;i<DD;i++) a = fmaf(y2[i], W2[i*DD+tid], a);
    y3[tid] = a>0.f? a : 0.f;
  }
  __syncthreads();
  if (tid<2){
    float a=bc[tid];
    #pragma unroll
    for (int i=0;i<DD;i++) a = fmaf(y3[i], Wc[i*2+tid], a);
    out[tid] = a;                       // fp32 output
  }
}

extern "C" void kernel_launch(void* const* d_in, const int* in_sizes, int n_in,
                              void* d_out, int out_size, void* d_ws, size_t ws_size,
                              hipStream_t stream) {
  const int N = in_sizes[0];
  const int E = in_sizes[1];
  const float* tok_emb   = (const float*)d_in[4];
  const float* e_tok_emb = (const float*)d_in[5];
  const float* W_ni  = (const float*)d_in[6];
  const float* W_nj  = (const float*)d_in[7];
  const float* W_fij = (const float*)d_in[8];
  const float* b_e   = (const float*)d_in[9];
  const float* attn  = (const float*)d_in[10];
  const float* W_nd  = (const float*)d_in[11];

  char* p = (char*)d_ws;
  auto alloc = [&](size_t bytes)->char* {
    char* r = p; p += (bytes + 255) & ~(size_t)255; return r;
  };
  // sde8 aliases h+pad+lbuf; btmp aliases ebuf; all dead at setup
  int* iflag = (int*)alloc(256);
  unsigned long long* sel = (unsigned long long*)alloc(256);
  unsigned long long* cand = (unsigned long long*)alloc(256*TOPK*8);
  int* bcnt = (int*)alloc(HNB*4);
  int* bbase = (int*)alloc((HNB+1)*4);
  int* gcur = (int*)alloc(HNB*4);
  int* csroff = (int*)alloc((size_t)(N+1)*4);
  unsigned* csr_sd = (unsigned*)alloc((size_t)(E+32)*4);
  float* h = (float*)alloc((size_t)N*DD*4);                     // fp32, final only
  alloc((size_t)N*DD*2);                                        // pad: keeps sde8 span valid
  unsigned short* lbuf = (unsigned short*)alloc((size_t)(E+32)*2);
  unsigned short* h16a = (unsigned short*)alloc((size_t)N*DD*2);
  unsigned short* h16b = (unsigned short*)alloc((size_t)N*DD*2);
  unsigned short* hA16 = (unsigned short*)alloc((size_t)N*DD*2);
  unsigned short* hB16 = (unsigned short*)alloc((size_t)N*DD*2);
  unsigned short* ebuf = (unsigned short*)alloc((size_t)(E+32)*DD*2);
  uint2* sde8 = (uint2*)h;                        // alias: spans h+pad+lbuf (12.8 MB)
  uint2* btmp = (uint2*)ebuf;                     // alias: ebuf dead until k_fill
  unsigned long long* keys = (unsigned long long*)lbuf;  // alias: lbuf dead after last aggr

  const int NB = (N + NPB - 1) / NPB;             // buckets (196 @ N=50k)
  const int NECH = (E + BCH - 1) / BCH;

  hipLaunchKernelGGL(k_detect, dim3(1), dim3(1024), 0, stream, (const int*)d_in[2], iflag, bcnt);
  hipLaunchKernelGGL(k_init, dim3((int)(((long)N*8+255)/256)), dim3(256), 0, stream,
                     d_in[0], tok_emb, h16a, iflag, N);
  hipLaunchKernelGGL(k_hist, dim3(NECH), dim3(256), 0, stream,
                     d_in[3], bcnt, iflag, E, NB);
  hipLaunchKernelGGL(k_bscan, dim3(1), dim3(1024), 0, stream, bcnt, bbase, gcur, NB, E);
  hipLaunchKernelGGL(k_bucket, dim3(NECH), dim3(256), 0, stream,
                     d_in[2], d_in[3], gcur, btmp, iflag, E, NB);
  hipLaunchKernelGGL(k_bsort, dim3(NB), dim3(256), 0, stream, bbase, btmp, sde8, csroff, N, NB);
  hipLaunchKernelGGL(k_fill, dim3((int)(((long)E*4+255)/256)), dim3(256), 0, stream,
                     sde8, d_in[1], e_tok_emb, csr_sd, ebuf, iflag, E);

  int nb_node = (N+7)/8;
  int ntiles = (E+15)/16;
  hipLaunchKernelGGL(k_nodeAB, dim3(nb_node), dim3(256), 0, stream,
                     h16a, W_ni, W_nj, hA16, hB16, N);
  unsigned short* hcur = h16a;
  unsigned short* hnext = h16b;
  for (int l=0; l<NLAYERS; l++){
    const float* Wf  = W_fij + (size_t)l*DD*DD;
    const float* bl  = b_e   + (size_t)l*DD;
    const float* at  = attn  + (size_t)l*DD;
    const float* Wnd = W_nd  + (size_t)l*DD*DD;
    int last = (l == NLAYERS-1);
    hipLaunchKernelGGL(k_edge, dim3(2048), dim3(256), 0, stream,
                       ebuf, hA16, hB16, csr_sd, Wf, bl, at, lbuf, ntiles,
                       last ? 0 : 1);
    const float* WnA = last ? W_ni : (W_ni + (size_t)(l+1)*DD*DD);
    const float* WnB = last ? W_nj : (W_nj + (size_t)(l+1)*DD*DD);
    hipLaunchKernelGGL(k_aggrP, dim3(nb_node), dim3(256), 0, stream,
                       hcur, lbuf, csroff, csr_sd, Wnd, WnA, WnB,
                       hnext, hA16, hB16, h, N, last);
    unsigned short* tmp = hcur; hcur = hnext; hnext = tmp;
  }

  hipLaunchKernelGGL(k_keys, dim3((N+255)/256), dim3(256), 0, stream, h, keys, N);
  hipLaunchKernelGGL(k_ptop, dim3(256), dim3(256), 0, stream, keys, N, cand);
  hipLaunchKernelGGL(k_ptop, dim3(1), dim3(256), 0, stream, cand, 256*TOPK, sel);
  hipLaunchKernelGGL(k_head, dim3(1), dim3(256), 0, stream,
                     h, sel,
                     (const float*)d_in[12], (const float*)d_in[13],
                     (const float*)d_in[14], (const float*)d_in[15],
                     (const float*)d_in[16], (const float*)d_in[17],
                     (const float*)d_in[18], (const float*)d_in[19],
                     (float*)d_out, N);
}